// Round 5
// baseline (71485.974 us; speedup 1.0000x reference)
//
#include <hip/hip_runtime.h>
#include <cstdint>

// RoleConditionedLSTMDecoder on MI355X (gfx950) — R13.
// = R10 tile code (256x256 8-phase counted-vmcnt GEMM, best 21.78 ms), with
//   the 3 dispatches per step FUSED into ONE dispatch of 1760 blocks
//   (704 S1 | 704 S2 | 352 S3x2) linked by monotonic device-scope flag
//   counters (done0/done1[bm], threshold 8*(t+1)). Producers: threadfence +
//   barrier + release atomicAdd. Consumers: tid0 spin (s_sleep) + barrier +
//   per-wave agent acquire fence (buffer_inv -> no stale L1). Deadlock-free:
//   CP starts workgroups in flat-ID order, so all producers start before any
//   consumer; XCD-swizzled IDs align producer/consumer rounds (S1 round r
//   completes exactly the bm set S2 round r needs). R12's noinline spill
//   disaster (VGPR=128) avoided: everything force-inlined.

#define DEVI __device__ __forceinline__

typedef __bf16 bf16x8 __attribute__((ext_vector_type(8)));
typedef float  f32x4  __attribute__((ext_vector_type(4)));
typedef float  f32x2  __attribute__((ext_vector_type(2)));
typedef unsigned short u16x4 __attribute__((ext_vector_type(4)));

static constexpr int NROWS = 22528;   // B*P
static constexpr int T_STEPS = 100;
static constexpr int NBM = 176;       // 22528/128 row-tiles (k_static only)

DEVI unsigned short f2bf(float f) {
  unsigned u = __float_as_uint(f);
  u = u + 0x7FFFu + ((u >> 16) & 1u);   // RNE
  return (unsigned short)(u >> 16);
}
DEVI float bf2f(unsigned short h) { return __uint_as_float(((unsigned)h) << 16); }

DEVI float fast_sigmoid(float x) {
  float e = __builtin_amdgcn_exp2f(-1.442695041f * x);
  return __builtin_amdgcn_rcpf(1.0f + e);
}
DEVI float fast_tanh(float x) {
  float e = __builtin_amdgcn_exp2f(2.885390082f * x);   // e^(2x)
  return 1.0f - 2.0f * __builtin_amdgcn_rcpf(e + 1.0f);
}

DEVI void async_copy16(const void* g, void* l) {
  __builtin_amdgcn_global_load_lds(
      (const __attribute__((address_space(1))) void*)g,
      (__attribute__((address_space(3))) void*)l, 16, 0, 0);
}

// ---------------- 128x128 GEMM core (k_static only) — proven ----------------
template <int KITERS, int KSWITCH>
DEVI void gemm_core(const unsigned short* __restrict__ A1, int lda1,
                    const unsigned short* __restrict__ A2, int lda2,
                    const unsigned short* __restrict__ B1, int ldb1,
                    const unsigned short* __restrict__ B2, int ldb2,
                    unsigned short* lds, f32x4 acc[4][4], int tid) {
  const int lane = tid & 63, wid = tid >> 6;
  const int wm = wid & 1, wn = wid >> 1;
  const int c16 = lane & 15, q = lane >> 4;
#pragma unroll
  for (int i = 0; i < 4; ++i)
#pragma unroll
    for (int j = 0; j < 4; ++j) acc[i][j] = f32x4{0.f, 0.f, 0.f, 0.f};
#pragma unroll
  for (int kt = 0; kt < KITERS; ++kt) {
    const bool sec = (kt >= KSWITCH);
    const unsigned short* Ab = sec ? A2 : A1;
    const unsigned short* Bb = sec ? B2 : B1;
    const int lda = sec ? lda2 : lda1;
    const int ldb = sec ? ldb2 : ldb1;
    const int kk = (sec ? (kt - KSWITCH) : kt) * 64;
    __syncthreads();
#pragma unroll
    for (int rd = 0; rd < 4; ++rd) {
      int p = rd * 256 + tid;
      int row = p >> 3, u = p & 7, ch = u ^ (row & 7);
      async_copy16(Ab + row * lda + kk + ch * 8, lds + p * 8);
      async_copy16(Bb + row * ldb + kk + ch * 8, lds + 8192 + p * 8);
    }
    __syncthreads();
#pragma unroll
    for (int s = 0; s < 2; ++s) {
      bf16x8 a[4], b[4];
#pragma unroll
      for (int mf = 0; mf < 4; ++mf) {
        int row = wm * 64 + mf * 16 + c16;
        int slot = row * 8 + ((s * 4 + q) ^ (row & 7));
        a[mf] = *(const bf16x8*)(lds + slot * 8);
      }
#pragma unroll
      for (int nf = 0; nf < 4; ++nf) {
        int row = wn * 64 + nf * 16 + c16;
        int slot = row * 8 + ((s * 4 + q) ^ (row & 7));
        b[nf] = *(const bf16x8*)(lds + 8192 + slot * 8);
      }
#pragma unroll
      for (int mf = 0; mf < 4; ++mf)
#pragma unroll
        for (int nf = 0; nf < 4; ++nf)
          acc[mf][nf] = __builtin_amdgcn_mfma_f32_16x16x32_bf16(a[mf], b[nf], acc[mf][nf], 0, 0, 0);
    }
  }
}

// ---------------- prep ----------------
DEVI int orig_row(int j) {
  int tile = j >> 7, rem = j & 127;
  int half = rem >> 6, g = (rem >> 4) & 3, cc = rem & 15;
  return g * 512 + (tile * 32 + half * 16 + cc);
}

__global__ void k_prep_w(const float* __restrict__ Whh0, const float* __restrict__ Wih1,
                         const float* __restrict__ Whh1, const float* __restrict__ Wih0,
                         const float* __restrict__ Wfc1, const float* __restrict__ b0,
                         const float* __restrict__ b1,
                         unsigned short* __restrict__ W0p, unsigned short* __restrict__ Wc1p,
                         unsigned short* __restrict__ Wsp, unsigned short* __restrict__ Wfc1b,
                         float* __restrict__ Wposx, float* __restrict__ Wposy,
                         float* __restrict__ b0p4, float* __restrict__ b1p4) {
  int j = blockIdx.x;       // 0..2047
  int k = threadIdx.x;      // 0..511
  int o = orig_row(j);
  W0p[j * 512 + k]         = f2bf(Whh0[o * 512 + k]);
  Wc1p[j * 1024 + k]       = f2bf(Wih1[o * 512 + k]);
  Wc1p[j * 1024 + 512 + k] = f2bf(Whh1[o * 512 + k]);
  if (k < 384) Wsp[j * 384 + k] = (k < 322) ? f2bf(Wih0[o * 324 + 2 + k]) : (unsigned short)0;
  if (k == 0) {
    int g = (j >> 4) & 3;
    int cg = (j >> 7) * 32 + ((j >> 6) & 1) * 16 + (j & 15);
    Wposx[cg * 4 + g] = Wih0[o * 324 + 0];
    Wposy[cg * 4 + g] = Wih0[o * 324 + 1];
    b0p4[cg * 4 + g] = b0[o];
    b1p4[cg * 4 + g] = b1[o];
  }
  if (j < 256) Wfc1b[j * 512 + k] = f2bf(Wfc1[j * 512 + k]);
}

__global__ void k_init_xs(const float* __restrict__ ball, const float* __restrict__ ctx,
                          const int* __restrict__ roles, const float* __restrict__ role_table,
                          unsigned short* __restrict__ Xs) {
  int n = blockIdx.x, col = threadIdx.x;  // 22528 x 384
  int b = n / 22;
  float v;
  if (col < 2)        v = ball[b * 2 + col];
  else if (col < 258) v = ctx[(size_t)n * 256 + col - 2];
  else if (col < 322) v = role_table[roles[n] * 64 + col - 258];
  else                v = 0.f;
  Xs[(size_t)n * 384 + col] = f2bf(v);
}

__global__ void k_init_state(const float* __restrict__ pos0, const float* __restrict__ Winit,
                             const float* __restrict__ binit, unsigned short* __restrict__ Hcat,
                             float* __restrict__ c0, float* __restrict__ c1,
                             float* __restrict__ posb,
                             unsigned int* __restrict__ done0,
                             unsigned int* __restrict__ done1) {
  int idx = blockIdx.x * 256 + threadIdx.x;     // N*512
  if (idx >= NROWS * 512) return;
  int n = idx >> 9, c = idx & 511;
  float px = pos0[n * 2 + 0], py = pos0[n * 2 + 1];
  float h0 = binit[c] + Winit[c * 2 + 0] * px + Winit[c * 2 + 1] * py;
  Hcat[(size_t)n * 1024 + c] = f2bf(h0);
  Hcat[(size_t)n * 1024 + 512 + c] = 0;   // h1 = 0
  c0[idx] = 0.f;
  c1[idx] = 0.f;
  if (c < 2) posb[n * 2 + c] = pos0[n * 2 + c];
  if (idx < 88) { done0[idx] = 0u; done1[idx] = 0u; }   // re-zeroed every replay
}

// static_proj packed: SP2[row*512+cg] = ushort4{i,f,g,o} + b0 — SP path only
__global__ __launch_bounds__(256) void k_static(const unsigned short* __restrict__ Xs,
                                                const unsigned short* __restrict__ Wsp,
                                                const float* __restrict__ b0p4,
                                                unsigned short* __restrict__ SP2) {
  __shared__ __align__(16) unsigned short lds[16384];
  int tid = threadIdx.x, bn = blockIdx.x, bm = blockIdx.y;
  f32x4 acc[4][4];
  const unsigned short* Ab = Xs + (size_t)bm * 128 * 384;
  const unsigned short* Bb = Wsp + (size_t)bn * 128 * 384;
  gemm_core<6, 6>(Ab, 384, Ab, 384, Bb, 384, Bb, 384, lds, acc, tid);
  int lane = tid & 63, wid = tid >> 6, wm = wid & 1, wn = wid >> 1;
  int c16 = lane & 15, q = lane >> 4;
  int cg = bn * 32 + wn * 16 + c16;
  f32x4 bb = *(const f32x4*)&b0p4[cg * 4];
#pragma unroll
  for (int mf = 0; mf < 4; ++mf) {
    int row0 = bm * 128 + wm * 64 + mf * 16 + q * 4;
#pragma unroll
    for (int r = 0; r < 4; ++r) {
      u16x4 v;
      v.x = f2bf(acc[mf][0][r] + bb.x);
      v.y = f2bf(acc[mf][1][r] + bb.y);
      v.z = f2bf(acc[mf][2][r] + bb.z);
      v.w = f2bf(acc[mf][3][r] + bb.w);
      ((u16x4*)SP2)[(size_t)(row0 + r) * 512 + cg] = v;
    }
  }
}

// ---------------- 256x256 8-phase GEMM core (S1/S2) — R10, proven ----------------
struct GemmSrc {
  const unsigned short *A1, *A2, *B1, *B2;
  int ldA1, ldA2, ldB1, ldB2;
};

template <int KT, int KSW>
DEVI void stage_q(const GemmSrc& g, int t, int s, int isB, unsigned short* dst, int tid) {
  int tt = (t >= KT) ? (t - 2) : t;        // tail: clamp source, keep counts
  const bool sec = (tt >= KSW);
  const unsigned short* base;
  int ld;
  if (isB) { base = sec ? g.B2 : g.B1; ld = sec ? g.ldB2 : g.ldB1; }
  else     { base = sec ? g.A2 : g.A1; ld = sec ? g.ldA2 : g.ldA1; }
  base += (sec ? (tt - KSW) : tt) * 64 + s * 32;
#pragma unroll
  for (int rd = 0; rd < 2; ++rd) {
    int p = rd * 512 + tid;
    int row = p >> 2, u = p & 3, ch = u ^ ((row >> 1) & 3);
    async_copy16(base + row * ld + ch * 8, dst + p * 8);
  }
}

#define GBAR   asm volatile("s_barrier" ::: "memory")
#define VMCNT4 asm volatile("s_waitcnt vmcnt(4)" ::: "memory")

template <int KT, int KSW>
DEVI void gemm8(const GemmSrc& g, unsigned short* lds, f32x4 acc[8][4], int tid) {
  const int lane = tid & 63, wid = tid >> 6;
  const int wm = wid >> 2, wn = wid & 3;
  const int c16 = lane & 15, q = lane >> 4;
#pragma unroll
  for (int i = 0; i < 8; ++i)
#pragma unroll
    for (int j = 0; j < 4; ++j) acc[i][j] = f32x4{0.f, 0.f, 0.f, 0.f};
  unsigned short* A00 = lds;
  unsigned short* A01 = lds + 8192;
  unsigned short* B00 = lds + 16384;
  unsigned short* B01 = lds + 24576;
  unsigned short* A10 = lds + 32768;
  unsigned short* A11 = lds + 40960;
  unsigned short* B10 = lds + 49152;
  unsigned short* B11 = lds + 57344;
  const int rowA0 = wm * 128 + c16;
  const int rowB0 = wn * 64 + c16;
  stage_q<KT, KSW>(g, 0, 0, 0, A00, tid);
  stage_q<KT, KSW>(g, 0, 0, 1, B00, tid);
  stage_q<KT, KSW>(g, 0, 1, 0, A01, tid);
  stage_q<KT, KSW>(g, 0, 1, 1, B01, tid);
  stage_q<KT, KSW>(g, 1, 0, 0, A10, tid);
  stage_q<KT, KSW>(g, 1, 0, 1, B10, tid);
  VMCNT4;
  GBAR;
  bf16x8 a[4], b[4];

#define LOADA(BASE, MG)                                                        \
  _Pragma("unroll")                                                            \
  for (int f = 0; f < 4; ++f) {                                                \
    int row = rowA0 + ((MG) * 4 + f) * 16;                                     \
    a[f] = *(const bf16x8*)((BASE) + (row * 4 + (q ^ ((row >> 1) & 3))) * 8);  \
  }
#define LOADB(BASE)                                                            \
  _Pragma("unroll")                                                            \
  for (int f = 0; f < 4; ++f) {                                                \
    int row = rowB0 + f * 16;                                                  \
    b[f] = *(const bf16x8*)((BASE) + (row * 4 + (q ^ ((row >> 1) & 3))) * 8);  \
  }
#define MFG(MG)                                                                \
  __builtin_amdgcn_s_setprio(1);                                               \
  _Pragma("unroll")                                                            \
  for (int f = 0; f < 4; ++f)                                                  \
    _Pragma("unroll")                                                          \
    for (int nf = 0; nf < 4; ++nf)                                             \
      acc[(MG) * 4 + f][nf] = __builtin_amdgcn_mfma_f32_16x16x32_bf16(         \
          a[f], b[nf], acc[(MG) * 4 + f][nf], 0, 0, 0);                        \
  __builtin_amdgcn_s_setprio(0);                                               \
  __builtin_amdgcn_sched_barrier(0);

#pragma unroll 1
  for (int it = 0; it < KT / 2; ++it) {
    const int t0 = 2 * it;
    LOADA(A00, 0); LOADB(B00);
    stage_q<KT, KSW>(g, t0 + 1, 1, 0, A11, tid);
    GBAR; MFG(0); GBAR;
    LOADA(A00, 1);
    stage_q<KT, KSW>(g, t0 + 1, 1, 1, B11, tid);
    GBAR; MFG(1); GBAR;
    LOADA(A01, 0); LOADB(B01);
    stage_q<KT, KSW>(g, t0 + 2, 0, 0, A00, tid);
    GBAR; MFG(0); GBAR;
    LOADA(A01, 1);
    stage_q<KT, KSW>(g, t0 + 2, 0, 1, B00, tid);
    GBAR; MFG(1); VMCNT4; GBAR;
    LOADA(A10, 0); LOADB(B10);
    stage_q<KT, KSW>(g, t0 + 2, 1, 0, A01, tid);
    GBAR; MFG(0); GBAR;
    LOADA(A10, 1);
    stage_q<KT, KSW>(g, t0 + 2, 1, 1, B01, tid);
    GBAR; MFG(1); GBAR;
    LOADA(A11, 0); LOADB(B11);
    stage_q<KT, KSW>(g, t0 + 3, 0, 0, A10, tid);
    GBAR; MFG(0); GBAR;
    LOADA(A11, 1);
    stage_q<KT, KSW>(g, t0 + 3, 0, 1, B10, tid);
    GBAR; MFG(1); VMCNT4; GBAR;
  }
  asm volatile("s_waitcnt vmcnt(0)" ::: "memory");   // drain tail fakes
#undef LOADA
#undef LOADB
#undef MFG
}

// XCD swizzle for 704-tile space: bm ≡ (l&7) (mod 8) -> A-panel reuse per XCD.
DEVI void swz704(int l, int& bn, int& bm) {
  int xcd = l & 7, ii = l >> 3;   // ii in 0..87
  bn = ii & 7;
  bm = (ii >> 3) * 8 + xcd;       // 11 bm per xcd
}

// ---------------- fused per-step kernel ----------------
// Blocks: [0,704) S1 | [704,1408) S2 | [1408,1760) S3 (2 tiles/block).
// Flags: monotonic counters, threshold 8*(t+1). Producer: fence+bar+rel-add.
// Consumer: tid0 spin + bar + per-wave agent acquire fence (L1 inv).
template <bool USE_SP>
__global__ __launch_bounds__(512, 2) void k_step(
    const unsigned short* __restrict__ cur, unsigned short* __restrict__ nxt,
    const unsigned short* __restrict__ Xs,
    const unsigned short* __restrict__ W0p, const unsigned short* __restrict__ Wsp,
    const unsigned short* __restrict__ SP2, const float* __restrict__ b0p4,
    const float* __restrict__ Wposx, const float* __restrict__ Wposy,
    float* __restrict__ posb, float* __restrict__ c0,
    const unsigned short* __restrict__ Wc1p, const float* __restrict__ b1p4,
    float* __restrict__ c1,
    const unsigned short* __restrict__ Wfc1b, const float* __restrict__ bfc1,
    const float* __restrict__ Wfc2, const float* __restrict__ bfc2,
    float* __restrict__ out, unsigned int* __restrict__ done0,
    unsigned int* __restrict__ done1, int t) {
  __shared__ __align__(16) unsigned short lds[65536];   // 128 KiB
  const int tid = threadIdx.x;
  const int bid = blockIdx.x;
  const unsigned thr = 8u * (unsigned)(t + 1);

  if (bid < 704) {
    // ---------------- S1 ----------------
    int bn, bm;
    swz704(bid, bn, bm);
    f32x4 acc[8][4];
    GemmSrc g;
    g.A1 = cur + (size_t)bm * 256 * 1024; g.ldA1 = 1024;
    g.B1 = W0p + (size_t)bn * 256 * 512;  g.ldB1 = 512;
    if constexpr (USE_SP) {
      g.A2 = g.A1; g.ldA2 = 1024; g.B2 = g.B1; g.ldB2 = 512;
      gemm8<8, 8>(g, lds, acc, tid);
    } else {
      g.A2 = Xs + (size_t)bm * 256 * 384;  g.ldA2 = 384;
      g.B2 = Wsp + (size_t)bn * 256 * 384; g.ldB2 = 384;
      gemm8<14, 8>(g, lds, acc, tid);
    }
    const int lane = tid & 63, wid = tid >> 6;
    const int wm = wid >> 2, wn = wid & 3;
    const int c16 = lane & 15, q = lane >> 4;
    const int cg = bn * 64 + (wn >> 1) * 32 + (wn & 1) * 16 + c16;
    f32x4 wpx = *(const f32x4*)&Wposx[cg * 4];
    f32x4 wpy = *(const f32x4*)&Wposy[cg * 4];
    f32x4 sb = f32x4{0.f, 0.f, 0.f, 0.f};
    if constexpr (!USE_SP) sb = *(const f32x4*)&b0p4[cg * 4];
#pragma unroll
    for (int mf = 0; mf < 8; ++mf) {
      int row0 = bm * 256 + wm * 128 + mf * 16 + q * 4;
      f32x4 cold = *(const f32x4*)&c0[(size_t)cg * NROWS + row0];
      f32x4 cnew;
#pragma unroll
      for (int r = 0; r < 4; ++r) {
        size_t row = row0 + r;
        f32x2 pv = *(const f32x2*)&posb[row * 2];
        float s0 = sb.x, s1 = sb.y, s2 = sb.z, s3 = sb.w;
        if constexpr (USE_SP) {
          u16x4 sp = ((const u16x4*)SP2)[row * 512 + cg];
          s0 = bf2f(sp.x); s1 = bf2f(sp.y); s2 = bf2f(sp.z); s3 = bf2f(sp.w);
        }
        float gi = acc[mf][0][r] + s0 + pv.x * wpx.x + pv.y * wpy.x;
        float gf = acc[mf][1][r] + s1 + pv.x * wpx.y + pv.y * wpy.y;
        float gg = acc[mf][2][r] + s2 + pv.x * wpx.z + pv.y * wpy.z;
        float go = acc[mf][3][r] + s3 + pv.x * wpx.w + pv.y * wpy.w;
        float cn = fast_sigmoid(gf) * cold[r] + fast_sigmoid(gi) * fast_tanh(gg);
        cnew[r] = cn;
        nxt[row * 1024 + cg] = f2bf(fast_sigmoid(go) * fast_tanh(cn));
      }
      *(f32x4*)&c0[(size_t)cg * NROWS + row0] = cnew;
    }
    __threadfence();        // per-thread: drain stores to L2, agent-visible
    __syncthreads();        // all waves' stores complete before the flag
    if (tid == 0)
      __hip_atomic_fetch_add(&done0[bm], 1u, __ATOMIC_RELEASE, __HIP_MEMORY_SCOPE_AGENT);
  } else if (bid < 1408) {
    // ---------------- S2 ----------------
    int bn, bm;
    swz704(bid - 704, bn, bm);
    if (tid == 0) {
      while (__hip_atomic_load(&done0[bm], __ATOMIC_ACQUIRE, __HIP_MEMORY_SCOPE_AGENT) < thr)
        __builtin_amdgcn_s_sleep(2);
    }
    __syncthreads();
    __builtin_amdgcn_fence(__ATOMIC_ACQUIRE, "agent");   // per-wave L1 inv
    f32x4 acc[8][4];
    GemmSrc g;
    g.A1 = nxt + (size_t)bm * 256 * 1024;         g.ldA1 = 1024;   // h0_t
    g.A2 = cur + (size_t)bm * 256 * 1024 + 512;   g.ldA2 = 1024;   // h1_{t-1}
    g.B1 = Wc1p + (size_t)bn * 256 * 1024;        g.ldB1 = 1024;
    g.B2 = g.B1 + 512;                            g.ldB2 = 1024;
    gemm8<16, 8>(g, lds, acc, tid);
    const int lane = tid & 63, wid = tid >> 6;
    const int wm = wid >> 2, wn = wid & 3;
    const int c16 = lane & 15, q = lane >> 4;
    const int cg = bn * 64 + (wn >> 1) * 32 + (wn & 1) * 16 + c16;
    f32x4 bv = *(const f32x4*)&b1p4[cg * 4];
#pragma unroll
    for (int mf = 0; mf < 8; ++mf) {
      int row0 = bm * 256 + wm * 128 + mf * 16 + q * 4;
      f32x4 cold = *(const f32x4*)&c1[(size_t)cg * NROWS + row0];
      f32x4 cnew;
#pragma unroll
      for (int r = 0; r < 4; ++r) {
        size_t row = row0 + r;
        float gi = acc[mf][0][r] + bv.x;
        float gf = acc[mf][1][r] + bv.y;
        float gg = acc[mf][2][r] + bv.z;
        float go = acc[mf][3][r] + bv.w;
        float cn = fast_sigmoid(gf) * cold[r] + fast_sigmoid(gi) * fast_tanh(gg);
        cnew[r] = cn;
        nxt[row * 1024 + 512 + cg] = f2bf(fast_sigmoid(go) * fast_tanh(cn));
      }
      *(f32x4*)&c1[(size_t)cg * NROWS + row0] = cnew;
    }
    __threadfence();
    __syncthreads();
    if (tid == 0)
      __hip_atomic_fetch_add(&done1[bm], 1u, __ATOMIC_RELEASE, __HIP_MEMORY_SCOPE_AGENT);
  } else {
    // ---------------- S3 (two 32-row tiles per block) ----------------
    const int s = bid - 1408;              // 0..351
    const int inst = tid >> 8, t256 = tid & 255;
    const int b32 = 2 * s + inst;          // 0..703; (2s)>>3 == (2s+1)>>3
    if (tid == 0) {
      while (__hip_atomic_load(&done1[b32 >> 3], __ATOMIC_ACQUIRE, __HIP_MEMORY_SCOPE_AGENT) < thr)
        __builtin_amdgcn_s_sleep(2);
    }
    __syncthreads();
    __builtin_amdgcn_fence(__ATOMIC_ACQUIRE, "agent");
    unsigned short* ldsI = lds + inst * 32768;
    unsigned short* ldsA = ldsI;                       // 32*64
    unsigned short* ldsB = ldsI + 2048;                // 256*64
    float* wfc2s = (float*)(ldsI + 2048 + 16384);      // 512
    float* red   = wfc2s + 512;                        // 32*8
    wfc2s[t256] = Wfc2[t256];
    wfc2s[t256 + 256] = Wfc2[t256 + 256];
    int lane = t256 & 63, wid = t256 >> 6;
    int c16 = lane & 15, q = lane >> 4;
    f32x4 acc[2][4];
#pragma unroll
    for (int ii = 0; ii < 2; ++ii)
#pragma unroll
      for (int jj = 0; jj < 4; ++jj) acc[ii][jj] = f32x4{0.f, 0.f, 0.f, 0.f};
    const unsigned short* Ab = nxt + (size_t)b32 * 32 * 1024 + 512;
#pragma unroll
    for (int kt = 0; kt < 8; ++kt) {
      int k0 = kt * 64;
      __syncthreads();
      {
        int p = t256;
        int row = p >> 3, u = p & 7, ch = u ^ (row & 7);
        async_copy16(Ab + row * 1024 + k0 + ch * 8, ldsA + p * 8);
      }
#pragma unroll
      for (int rd = 0; rd < 8; ++rd) {
        int p = rd * 256 + t256;
        int row = p >> 3, u = p & 7, ch = u ^ (row & 7);
        async_copy16(Wfc1b + row * 512 + k0 + ch * 8, ldsB + p * 8);
      }
      __syncthreads();
#pragma unroll
      for (int ss = 0; ss < 2; ++ss) {
        bf16x8 a[2], b[4];
#pragma unroll
        for (int mf = 0; mf < 2; ++mf) {
          int row = mf * 16 + c16;
          int slot = row * 8 + ((ss * 4 + q) ^ (row & 7));
          a[mf] = *(const bf16x8*)(ldsA + slot * 8);
        }
#pragma unroll
        for (int nf = 0; nf < 4; ++nf) {
          int row = wid * 64 + nf * 16 + c16;
          int slot = row * 8 + ((ss * 4 + q) ^ (row & 7));
          b[nf] = *(const bf16x8*)(ldsB + slot * 8);
        }
#pragma unroll
        for (int mf = 0; mf < 2; ++mf)
#pragma unroll
          for (int nf = 0; nf < 4; ++nf)
            acc[mf][nf] = __builtin_amdgcn_mfma_f32_16x16x32_bf16(a[mf], b[nf], acc[mf][nf], 0, 0, 0);
      }
    }
    float part[2][2][4];
#pragma unroll
    for (int d = 0; d < 2; ++d)
#pragma unroll
      for (int mf = 0; mf < 2; ++mf)
#pragma unroll
        for (int r = 0; r < 4; ++r) part[d][mf][r] = 0.f;
#pragma unroll
    for (int nf = 0; nf < 4; ++nf) {
      int col = wid * 64 + nf * 16 + c16;
      float w0 = wfc2s[col], w1 = wfc2s[256 + col], bv = bfc1[col];
#pragma unroll
      for (int mf = 0; mf < 2; ++mf)
#pragma unroll
        for (int r = 0; r < 4; ++r) {
          float v = acc[mf][nf][r] + bv;
          v = v > 0.f ? v : 0.f;
          part[0][mf][r] += v * w0;
          part[1][mf][r] += v * w1;
        }
    }
#pragma unroll
    for (int st = 1; st < 16; st <<= 1)
#pragma unroll
      for (int d = 0; d < 2; ++d)
#pragma unroll
        for (int mf = 0; mf < 2; ++mf)
#pragma unroll
          for (int r = 0; r < 4; ++r)
            part[d][mf][r] += __shfl_xor(part[d][mf][r], st, 64);
    if (c16 == 0) {
#pragma unroll
      for (int mf = 0; mf < 2; ++mf)
#pragma unroll
        for (int r = 0; r < 4; ++r) {
          int rl = mf * 16 + q * 4 + r;
          red[rl * 8 + wid * 2 + 0] = part[0][mf][r];
          red[rl * 8 + wid * 2 + 1] = part[1][mf][r];
        }
    }
    __syncthreads();
    if (t256 < 64) {
      int rl = t256 >> 1, d = t256 & 1;
      float sum = red[rl * 8 + d] + red[rl * 8 + 2 + d] + red[rl * 8 + 4 + d]
                + red[rl * 8 + 6 + d] + bfc2[d];
      int rg = b32 * 32 + rl;
      out[((size_t)rg * T_STEPS + t) * 2 + d] = sum;
      posb[rg * 2 + d] = sum;
    }
  }
}

// ---------------- launch ----------------
extern "C" void kernel_launch(void* const* d_in, const int* in_sizes, int n_in,
                              void* d_out, int out_size, void* d_ws, size_t ws_size,
                              hipStream_t stream) {
  (void)in_sizes; (void)n_in; (void)out_size;
  const float* ctx   = (const float*)d_in[0];
  const float* pos0  = (const float*)d_in[1];
  const float* ball  = (const float*)d_in[2];
  const int*   roles = (const int*)d_in[3];
  const float* role_table = (const float*)d_in[5];
  const float* Wih0 = (const float*)d_in[6];
  const float* Whh0 = (const float*)d_in[7];
  const float* b0   = (const float*)d_in[8];
  const float* Wih1 = (const float*)d_in[9];
  const float* Whh1 = (const float*)d_in[10];
  const float* b1   = (const float*)d_in[11];
  const float* Wfc1 = (const float*)d_in[12];
  const float* bfc1 = (const float*)d_in[13];
  const float* Wfc2 = (const float*)d_in[14];
  const float* bfc2 = (const float*)d_in[15];
  const float* Winit = (const float*)d_in[16];
  const float* binit = (const float*)d_in[17];
  float* out = (float*)d_out;

  char* w = (char*)d_ws;
  size_t used = 0;
  auto alloc = [&](size_t bytes) {
    char* p = w + used;
    used += (bytes + 255) & ~(size_t)255;
    return p;
  };
  unsigned short* W0p   = (unsigned short*)alloc((size_t)2048 * 512 * 2);
  unsigned short* Wc1p  = (unsigned short*)alloc((size_t)2048 * 1024 * 2);
  unsigned short* Wfc1b = (unsigned short*)alloc((size_t)256 * 512 * 2);
  float* Wposx = (float*)alloc(2048 * 4);
  float* Wposy = (float*)alloc(2048 * 4);
  float* b0p4  = (float*)alloc(2048 * 4);
  float* b1p4  = (float*)alloc(2048 * 4);
  float* posb  = (float*)alloc((size_t)NROWS * 2 * 4);
  unsigned int* done0 = (unsigned int*)alloc(88 * 4);
  unsigned int* done1 = (unsigned int*)alloc(88 * 4);
  unsigned short* Hc0 = (unsigned short*)alloc((size_t)NROWS * 1024 * 2);
  float* c0   = (float*)alloc((size_t)NROWS * 512 * 4);
  float* c1   = (float*)alloc((size_t)NROWS * 512 * 4);
  unsigned short* Hc1 = (unsigned short*)alloc((size_t)NROWS * 1024 * 2);

  const size_t SP_BYTES = (size_t)NROWS * 2048 * 2;           // 92.3 MB
  const bool use_sp = (ws_size >= used + SP_BYTES + (1u << 20));

  unsigned short *Xs, *Wsp, *SP2;
  if (use_sp) {
    SP2 = (unsigned short*)alloc(SP_BYTES);
    Xs  = Hc1;                                 // transient: dead before Hc1 is written
    Wsp = Hc1 + (size_t)NROWS * 384;
  } else {
    SP2 = Hc1;                                 // never dereferenced on lite path
    Xs  = (unsigned short*)alloc((size_t)NROWS * 384 * 2);
    Wsp = (unsigned short*)alloc((size_t)2048 * 384 * 2);
  }

  k_prep_w<<<2048, 512, 0, stream>>>(Whh0, Wih1, Whh1, Wih0, Wfc1, b0, b1,
                                     W0p, Wc1p, Wsp, Wfc1b, Wposx, Wposy, b0p4, b1p4);
  k_init_xs<<<NROWS, 384, 0, stream>>>(ball, ctx, roles, role_table, Xs);
  k_init_state<<<(NROWS * 512 + 255) / 256, 256, 0, stream>>>(pos0, Winit, binit, Hc0,
                                                              c0, c1, posb, done0, done1);

  if (use_sp) {
    dim3 gs(16, NBM);
    k_static<<<gs, 256, 0, stream>>>(Xs, Wsp, b0p4, SP2);
  }

  for (int t = 0; t < T_STEPS; ++t) {
    unsigned short* cur = (t & 1) ? Hc1 : Hc0;
    unsigned short* nxt = (t & 1) ? Hc0 : Hc1;
    if (use_sp)
      k_step<true><<<1760, 512, 0, stream>>>(cur, nxt, Xs, W0p, Wsp, SP2, b0p4,
                                             Wposx, Wposy, posb, c0, Wc1p, b1p4, c1,
                                             Wfc1b, bfc1, Wfc2, bfc2, out,
                                             done0, done1, t);
    else
      k_step<false><<<1760, 512, 0, stream>>>(cur, nxt, Xs, W0p, Wsp, SP2, b0p4,
                                              Wposx, Wposy, posb, c0, Wc1p, b1p4, c1,
                                              Wfc1b, bfc1, Wfc2, bfc2, out,
                                              done0, done1, t);
  }
}

// Round 6
// 22179.581 us; speedup vs baseline: 3.2231x; 3.2231x over previous
//
#include <hip/hip_runtime.h>
#include <cstdint>

// RoleConditionedLSTMDecoder on MI355X (gfx950) — R14.
// = R10 (proven 21.78 ms; 256x256 8-phase counted-vmcnt GEMM, 3 dispatches
//   per step) + COALESCED h-state writes. R12's counters showed WRITE_SIZE
//   467 MB/step vs ~140 logical (3.4x amplified): the epilogue's 2-byte
//   scattered nxt[row*1024+cg] stores create partial-sector HBM writes ->
//   ECC read-modify-write amplification (also inflating FETCH). Fix: each
//   block gathers its 256x64 bf16 h-tile in LDS (reusing dead GEMM buffers
//   after a post-gemm8 barrier so tail fake-stages have landed), then writes
//   16B chunks = full 128B row segments per wave-store. c0/c1 writes are
//   already 64B-sector aligned (verified) and unchanged.
// R13 lesson: no cross-block sync inside a dispatch (dispatch order is
//   undefined -> livelock). Stick to 3 serial dispatches.

#define DEVI __device__ __forceinline__

typedef __bf16 bf16x8 __attribute__((ext_vector_type(8)));
typedef float  f32x4  __attribute__((ext_vector_type(4)));
typedef float  f32x2  __attribute__((ext_vector_type(2)));
typedef unsigned short u16x4 __attribute__((ext_vector_type(4)));
typedef unsigned short u16x8 __attribute__((ext_vector_type(8)));

static constexpr int NROWS = 22528;   // B*P
static constexpr int T_STEPS = 100;
static constexpr int NBM = 176;       // 22528/128 row-tiles (k_static only)

DEVI unsigned short f2bf(float f) {
  unsigned u = __float_as_uint(f);
  u = u + 0x7FFFu + ((u >> 16) & 1u);   // RNE
  return (unsigned short)(u >> 16);
}
DEVI float bf2f(unsigned short h) { return __uint_as_float(((unsigned)h) << 16); }

DEVI float fast_sigmoid(float x) {
  float e = __builtin_amdgcn_exp2f(-1.442695041f * x);
  return __builtin_amdgcn_rcpf(1.0f + e);
}
DEVI float fast_tanh(float x) {
  float e = __builtin_amdgcn_exp2f(2.885390082f * x);   // e^(2x)
  return 1.0f - 2.0f * __builtin_amdgcn_rcpf(e + 1.0f);
}

DEVI void async_copy16(const void* g, void* l) {
  __builtin_amdgcn_global_load_lds(
      (const __attribute__((address_space(1))) void*)g,
      (__attribute__((address_space(3))) void*)l, 16, 0, 0);
}

// ---------------- 128x128 GEMM core (k_static only) — proven ----------------
template <int KITERS, int KSWITCH>
DEVI void gemm_core(const unsigned short* __restrict__ A1, int lda1,
                    const unsigned short* __restrict__ A2, int lda2,
                    const unsigned short* __restrict__ B1, int ldb1,
                    const unsigned short* __restrict__ B2, int ldb2,
                    unsigned short* lds, f32x4 acc[4][4], int tid) {
  const int lane = tid & 63, wid = tid >> 6;
  const int wm = wid & 1, wn = wid >> 1;
  const int c16 = lane & 15, q = lane >> 4;
#pragma unroll
  for (int i = 0; i < 4; ++i)
#pragma unroll
    for (int j = 0; j < 4; ++j) acc[i][j] = f32x4{0.f, 0.f, 0.f, 0.f};
#pragma unroll
  for (int kt = 0; kt < KITERS; ++kt) {
    const bool sec = (kt >= KSWITCH);
    const unsigned short* Ab = sec ? A2 : A1;
    const unsigned short* Bb = sec ? B2 : B1;
    const int lda = sec ? lda2 : lda1;
    const int ldb = sec ? ldb2 : ldb1;
    const int kk = (sec ? (kt - KSWITCH) : kt) * 64;
    __syncthreads();
#pragma unroll
    for (int rd = 0; rd < 4; ++rd) {
      int p = rd * 256 + tid;
      int row = p >> 3, u = p & 7, ch = u ^ (row & 7);
      async_copy16(Ab + row * lda + kk + ch * 8, lds + p * 8);
      async_copy16(Bb + row * ldb + kk + ch * 8, lds + 8192 + p * 8);
    }
    __syncthreads();
#pragma unroll
    for (int s = 0; s < 2; ++s) {
      bf16x8 a[4], b[4];
#pragma unroll
      for (int mf = 0; mf < 4; ++mf) {
        int row = wm * 64 + mf * 16 + c16;
        int slot = row * 8 + ((s * 4 + q) ^ (row & 7));
        a[mf] = *(const bf16x8*)(lds + slot * 8);
      }
#pragma unroll
      for (int nf = 0; nf < 4; ++nf) {
        int row = wn * 64 + nf * 16 + c16;
        int slot = row * 8 + ((s * 4 + q) ^ (row & 7));
        b[nf] = *(const bf16x8*)(lds + 8192 + slot * 8);
      }
#pragma unroll
      for (int mf = 0; mf < 4; ++mf)
#pragma unroll
        for (int nf = 0; nf < 4; ++nf)
          acc[mf][nf] = __builtin_amdgcn_mfma_f32_16x16x32_bf16(a[mf], b[nf], acc[mf][nf], 0, 0, 0);
    }
  }
}

// ---------------- prep ----------------
DEVI int orig_row(int j) {
  int tile = j >> 7, rem = j & 127;
  int half = rem >> 6, g = (rem >> 4) & 3, cc = rem & 15;
  return g * 512 + (tile * 32 + half * 16 + cc);
}

__global__ void k_prep_w(const float* __restrict__ Whh0, const float* __restrict__ Wih1,
                         const float* __restrict__ Whh1, const float* __restrict__ Wih0,
                         const float* __restrict__ Wfc1, const float* __restrict__ b0,
                         const float* __restrict__ b1,
                         unsigned short* __restrict__ W0p, unsigned short* __restrict__ Wc1p,
                         unsigned short* __restrict__ Wsp, unsigned short* __restrict__ Wfc1b,
                         float* __restrict__ Wposx, float* __restrict__ Wposy,
                         float* __restrict__ b0p4, float* __restrict__ b1p4) {
  int j = blockIdx.x;       // 0..2047
  int k = threadIdx.x;      // 0..511
  int o = orig_row(j);
  W0p[j * 512 + k]         = f2bf(Whh0[o * 512 + k]);
  Wc1p[j * 1024 + k]       = f2bf(Wih1[o * 512 + k]);
  Wc1p[j * 1024 + 512 + k] = f2bf(Whh1[o * 512 + k]);
  if (k < 384) Wsp[j * 384 + k] = (k < 322) ? f2bf(Wih0[o * 324 + 2 + k]) : (unsigned short)0;
  if (k == 0) {
    int g = (j >> 4) & 3;
    int cg = (j >> 7) * 32 + ((j >> 6) & 1) * 16 + (j & 15);
    Wposx[cg * 4 + g] = Wih0[o * 324 + 0];
    Wposy[cg * 4 + g] = Wih0[o * 324 + 1];
    b0p4[cg * 4 + g] = b0[o];
    b1p4[cg * 4 + g] = b1[o];
  }
  if (j < 256) Wfc1b[j * 512 + k] = f2bf(Wfc1[j * 512 + k]);
}

__global__ void k_init_xs(const float* __restrict__ ball, const float* __restrict__ ctx,
                          const int* __restrict__ roles, const float* __restrict__ role_table,
                          unsigned short* __restrict__ Xs) {
  int n = blockIdx.x, col = threadIdx.x;  // 22528 x 384
  int b = n / 22;
  float v;
  if (col < 2)        v = ball[b * 2 + col];
  else if (col < 258) v = ctx[(size_t)n * 256 + col - 2];
  else if (col < 322) v = role_table[roles[n] * 64 + col - 258];
  else                v = 0.f;
  Xs[(size_t)n * 384 + col] = f2bf(v);
}

__global__ void k_init_state(const float* __restrict__ pos0, const float* __restrict__ Winit,
                             const float* __restrict__ binit, unsigned short* __restrict__ Hcat,
                             float* __restrict__ c0, float* __restrict__ c1,
                             float* __restrict__ posb) {
  int idx = blockIdx.x * 256 + threadIdx.x;     // N*512
  if (idx >= NROWS * 512) return;
  int n = idx >> 9, c = idx & 511;
  float px = pos0[n * 2 + 0], py = pos0[n * 2 + 1];
  float h0 = binit[c] + Winit[c * 2 + 0] * px + Winit[c * 2 + 1] * py;
  Hcat[(size_t)n * 1024 + c] = f2bf(h0);
  Hcat[(size_t)n * 1024 + 512 + c] = 0;   // h1 = 0
  c0[idx] = 0.f;
  c1[idx] = 0.f;
  if (c < 2) posb[n * 2 + c] = pos0[n * 2 + c];
}

// static_proj packed: SP2[row*512+cg] = ushort4{i,f,g,o} + b0 — SP path only
__global__ __launch_bounds__(256) void k_static(const unsigned short* __restrict__ Xs,
                                                const unsigned short* __restrict__ Wsp,
                                                const float* __restrict__ b0p4,
                                                unsigned short* __restrict__ SP2) {
  __shared__ __align__(16) unsigned short lds[16384];
  int tid = threadIdx.x, bn = blockIdx.x, bm = blockIdx.y;
  f32x4 acc[4][4];
  const unsigned short* Ab = Xs + (size_t)bm * 128 * 384;
  const unsigned short* Bb = Wsp + (size_t)bn * 128 * 384;
  gemm_core<6, 6>(Ab, 384, Ab, 384, Bb, 384, Bb, 384, lds, acc, tid);
  int lane = tid & 63, wid = tid >> 6, wm = wid & 1, wn = wid >> 1;
  int c16 = lane & 15, q = lane >> 4;
  int cg = bn * 32 + wn * 16 + c16;
  f32x4 bb = *(const f32x4*)&b0p4[cg * 4];
#pragma unroll
  for (int mf = 0; mf < 4; ++mf) {
    int row0 = bm * 128 + wm * 64 + mf * 16 + q * 4;
#pragma unroll
    for (int r = 0; r < 4; ++r) {
      u16x4 v;
      v.x = f2bf(acc[mf][0][r] + bb.x);
      v.y = f2bf(acc[mf][1][r] + bb.y);
      v.z = f2bf(acc[mf][2][r] + bb.z);
      v.w = f2bf(acc[mf][3][r] + bb.w);
      ((u16x4*)SP2)[(size_t)(row0 + r) * 512 + cg] = v;
    }
  }
}

// ---------------- 256x256 8-phase GEMM core (S1/S2) — R10, proven ----------------
struct GemmSrc {
  const unsigned short *A1, *A2, *B1, *B2;
  int ldA1, ldA2, ldB1, ldB2;
};

template <int KT, int KSW>
DEVI void stage_q(const GemmSrc& g, int t, int s, int isB, unsigned short* dst, int tid) {
  int tt = (t >= KT) ? (t - 2) : t;        // tail: clamp source, keep counts
  const bool sec = (tt >= KSW);
  const unsigned short* base;
  int ld;
  if (isB) { base = sec ? g.B2 : g.B1; ld = sec ? g.ldB2 : g.ldB1; }
  else     { base = sec ? g.A2 : g.A1; ld = sec ? g.ldA2 : g.ldA1; }
  base += (sec ? (tt - KSW) : tt) * 64 + s * 32;
#pragma unroll
  for (int rd = 0; rd < 2; ++rd) {
    int p = rd * 512 + tid;
    int row = p >> 2, u = p & 3, ch = u ^ ((row >> 1) & 3);
    async_copy16(base + row * ld + ch * 8, dst + p * 8);
  }
}

#define GBAR   asm volatile("s_barrier" ::: "memory")
#define VMCNT4 asm volatile("s_waitcnt vmcnt(4)" ::: "memory")

template <int KT, int KSW>
DEVI void gemm8(const GemmSrc& g, unsigned short* lds, f32x4 acc[8][4], int tid) {
  const int lane = tid & 63, wid = tid >> 6;
  const int wm = wid >> 2, wn = wid & 3;
  const int c16 = lane & 15, q = lane >> 4;
#pragma unroll
  for (int i = 0; i < 8; ++i)
#pragma unroll
    for (int j = 0; j < 4; ++j) acc[i][j] = f32x4{0.f, 0.f, 0.f, 0.f};
  unsigned short* A00 = lds;
  unsigned short* A01 = lds + 8192;
  unsigned short* B00 = lds + 16384;
  unsigned short* B01 = lds + 24576;
  unsigned short* A10 = lds + 32768;
  unsigned short* A11 = lds + 40960;
  unsigned short* B10 = lds + 49152;
  unsigned short* B11 = lds + 57344;
  const int rowA0 = wm * 128 + c16;
  const int rowB0 = wn * 64 + c16;
  stage_q<KT, KSW>(g, 0, 0, 0, A00, tid);
  stage_q<KT, KSW>(g, 0, 0, 1, B00, tid);
  stage_q<KT, KSW>(g, 0, 1, 0, A01, tid);
  stage_q<KT, KSW>(g, 0, 1, 1, B01, tid);
  stage_q<KT, KSW>(g, 1, 0, 0, A10, tid);
  stage_q<KT, KSW>(g, 1, 0, 1, B10, tid);
  VMCNT4;
  GBAR;
  bf16x8 a[4], b[4];

#define LOADA(BASE, MG)                                                        \
  _Pragma("unroll")                                                            \
  for (int f = 0; f < 4; ++f) {                                                \
    int row = rowA0 + ((MG) * 4 + f) * 16;                                     \
    a[f] = *(const bf16x8*)((BASE) + (row * 4 + (q ^ ((row >> 1) & 3))) * 8);  \
  }
#define LOADB(BASE)                                                            \
  _Pragma("unroll")                                                            \
  for (int f = 0; f < 4; ++f) {                                                \
    int row = rowB0 + f * 16;                                                  \
    b[f] = *(const bf16x8*)((BASE) + (row * 4 + (q ^ ((row >> 1) & 3))) * 8);  \
  }
#define MFG(MG)                                                                \
  __builtin_amdgcn_s_setprio(1);                                               \
  _Pragma("unroll")                                                            \
  for (int f = 0; f < 4; ++f)                                                  \
    _Pragma("unroll")                                                          \
    for (int nf = 0; nf < 4; ++nf)                                             \
      acc[(MG) * 4 + f][nf] = __builtin_amdgcn_mfma_f32_16x16x32_bf16(         \
          a[f], b[nf], acc[(MG) * 4 + f][nf], 0, 0, 0);                        \
  __builtin_amdgcn_s_setprio(0);                                               \
  __builtin_amdgcn_sched_barrier(0);

#pragma unroll 1
  for (int it = 0; it < KT / 2; ++it) {
    const int t0 = 2 * it;
    LOADA(A00, 0); LOADB(B00);
    stage_q<KT, KSW>(g, t0 + 1, 1, 0, A11, tid);
    GBAR; MFG(0); GBAR;
    LOADA(A00, 1);
    stage_q<KT, KSW>(g, t0 + 1, 1, 1, B11, tid);
    GBAR; MFG(1); GBAR;
    LOADA(A01, 0); LOADB(B01);
    stage_q<KT, KSW>(g, t0 + 2, 0, 0, A00, tid);
    GBAR; MFG(0); GBAR;
    LOADA(A01, 1);
    stage_q<KT, KSW>(g, t0 + 2, 0, 1, B00, tid);
    GBAR; MFG(1); VMCNT4; GBAR;
    LOADA(A10, 0); LOADB(B10);
    stage_q<KT, KSW>(g, t0 + 2, 1, 0, A01, tid);
    GBAR; MFG(0); GBAR;
    LOADA(A10, 1);
    stage_q<KT, KSW>(g, t0 + 2, 1, 1, B01, tid);
    GBAR; MFG(1); GBAR;
    LOADA(A11, 0); LOADB(B11);
    stage_q<KT, KSW>(g, t0 + 3, 0, 0, A10, tid);
    GBAR; MFG(0); GBAR;
    LOADA(A11, 1);
    stage_q<KT, KSW>(g, t0 + 3, 0, 1, B10, tid);
    GBAR; MFG(1); VMCNT4; GBAR;
  }
  asm volatile("s_waitcnt vmcnt(0)" ::: "memory");   // drain tail fakes
#undef LOADA
#undef LOADB
#undef MFG
}

// XCD swizzle for 704-block grid: bm ≡ xcd (mod 8) -> A-panel reuse per XCD.
DEVI void swz704(int l, int& bn, int& bm) {
  int xcd = l & 7, ii = l >> 3;   // ii in 0..87
  bn = ii & 7;
  bm = (ii >> 3) * 8 + xcd;       // 11 bm per xcd
}

// ---------------- per-step ----------------
// S1: gates0 = h0_prev @ W0p^T (+ static) + pos@Wpos^T ; cell0 -> h0 into nxt[:,0:512]
template <bool USE_SP>
__global__ __launch_bounds__(512, 2) void k_s1_8(const unsigned short* __restrict__ cur,
                                                 const unsigned short* __restrict__ Xs,
                                                 const unsigned short* __restrict__ W0p,
                                                 const unsigned short* __restrict__ Wsp,
                                                 const unsigned short* __restrict__ SP2,
                                                 const float* __restrict__ b0p4,
                                                 const float* __restrict__ Wposx,
                                                 const float* __restrict__ Wposy,
                                                 const float* __restrict__ posb,
                                                 float* __restrict__ c0,
                                                 unsigned short* __restrict__ nxt) {
  __shared__ __align__(16) unsigned short lds[65536];   // 128 KiB static
  const int tid = threadIdx.x;
  int bn, bm;
  swz704(blockIdx.x, bn, bm);
  f32x4 acc[8][4];
  GemmSrc g;
  g.A1 = cur + (size_t)bm * 256 * 1024; g.ldA1 = 1024;
  g.B1 = W0p + (size_t)bn * 256 * 512;  g.ldB1 = 512;
  if constexpr (USE_SP) {
    g.A2 = g.A1; g.ldA2 = 1024; g.B2 = g.B1; g.ldB2 = 512;
    gemm8<8, 8>(g, lds, acc, tid);
  } else {
    g.A2 = Xs + (size_t)bm * 256 * 384;  g.ldA2 = 384;
    g.B2 = Wsp + (size_t)bn * 256 * 384; g.ldB2 = 384;
    gemm8<14, 8>(g, lds, acc, tid);
  }
  __syncthreads();   // all waves past final vmcnt(0): tail fake-stages landed
  const int lane = tid & 63, wid = tid >> 6;
  const int wm = wid >> 2, wn = wid & 3;
  const int c16 = lane & 15, q = lane >> 4;
  const int cgl = (wn >> 1) * 32 + (wn & 1) * 16 + c16;   // 0..63
  const int cg = bn * 64 + cgl;
  f32x4 wpx = *(const f32x4*)&Wposx[cg * 4];
  f32x4 wpy = *(const f32x4*)&Wposy[cg * 4];
  f32x4 sb = f32x4{0.f, 0.f, 0.f, 0.f};
  if constexpr (!USE_SP) sb = *(const f32x4*)&b0p4[cg * 4];
#pragma unroll
  for (int mf = 0; mf < 8; ++mf) {
    int rowl0 = wm * 128 + mf * 16 + q * 4;               // local row in [0,256)
    int row0 = bm * 256 + rowl0;
    f32x4 cold = *(const f32x4*)&c0[(size_t)cg * NROWS + row0];
    f32x4 cnew;
#pragma unroll
    for (int r = 0; r < 4; ++r) {
      size_t row = row0 + r;
      f32x2 pv = *(const f32x2*)&posb[row * 2];
      float s0 = sb.x, s1 = sb.y, s2 = sb.z, s3 = sb.w;
      if constexpr (USE_SP) {
        u16x4 sp = ((const u16x4*)SP2)[row * 512 + cg];
        s0 = bf2f(sp.x); s1 = bf2f(sp.y); s2 = bf2f(sp.z); s3 = bf2f(sp.w);
      }
      float gi = acc[mf][0][r] + s0 + pv.x * wpx.x + pv.y * wpy.x;
      float gf = acc[mf][1][r] + s1 + pv.x * wpx.y + pv.y * wpy.y;
      float gg = acc[mf][2][r] + s2 + pv.x * wpx.z + pv.y * wpy.z;
      float go = acc[mf][3][r] + s3 + pv.x * wpx.w + pv.y * wpy.w;
      float cn = fast_sigmoid(gf) * cold[r] + fast_sigmoid(gi) * fast_tanh(gg);
      cnew[r] = cn;
      lds[(rowl0 + r) * 64 + cgl] = f2bf(fast_sigmoid(go) * fast_tanh(cn));
    }
    *(f32x4*)&c0[(size_t)cg * NROWS + row0] = cnew;
  }
  __syncthreads();   // h-tile complete
  // gathered coalesced write: 256 rows x 64 cols bf16; per wave-store: 8 rows
  // x 128B full segments -> no partial HBM sectors (no RMW).
#pragma unroll
  for (int itw = 0; itw < 4; ++itw) {
    int p = itw * 512 + tid;
    int row = p >> 3, ch = p & 7;
    *(u16x8*)(nxt + (size_t)(bm * 256 + row) * 1024 + bn * 64 + ch * 8) =
        *(const u16x8*)(lds + row * 64 + ch * 8);
  }
}

// S2: gates1 = [h0_t | h1_prev] @ Wc1p^T + b1 ; cell1 -> h1 into nxt[:,512:]
__global__ __launch_bounds__(512, 2) void k_s2_8(const unsigned short* __restrict__ nxt_in,
                                                 const unsigned short* __restrict__ cur,
                                                 const unsigned short* __restrict__ Wc1p,
                                                 const float* __restrict__ b1p4,
                                                 float* __restrict__ c1,
                                                 unsigned short* __restrict__ nxt_out) {
  __shared__ __align__(16) unsigned short lds[65536];   // 128 KiB static
  const int tid = threadIdx.x;
  int bn, bm;
  swz704(blockIdx.x, bn, bm);
  f32x4 acc[8][4];
  GemmSrc g;
  g.A1 = nxt_in + (size_t)bm * 256 * 1024;      g.ldA1 = 1024;   // h0_t
  g.A2 = cur + (size_t)bm * 256 * 1024 + 512;   g.ldA2 = 1024;   // h1_{t-1}
  g.B1 = Wc1p + (size_t)bn * 256 * 1024;        g.ldB1 = 1024;
  g.B2 = g.B1 + 512;                            g.ldB2 = 1024;
  gemm8<16, 8>(g, lds, acc, tid);
  __syncthreads();   // tail fake-stages landed
  const int lane = tid & 63, wid = tid >> 6;
  const int wm = wid >> 2, wn = wid & 3;
  const int c16 = lane & 15, q = lane >> 4;
  const int cgl = (wn >> 1) * 32 + (wn & 1) * 16 + c16;
  const int cg = bn * 64 + cgl;
  f32x4 bv = *(const f32x4*)&b1p4[cg * 4];
#pragma unroll
  for (int mf = 0; mf < 8; ++mf) {
    int rowl0 = wm * 128 + mf * 16 + q * 4;
    int row0 = bm * 256 + rowl0;
    f32x4 cold = *(const f32x4*)&c1[(size_t)cg * NROWS + row0];
    f32x4 cnew;
#pragma unroll
    for (int r = 0; r < 4; ++r) {
      float gi = acc[mf][0][r] + bv.x;
      float gf = acc[mf][1][r] + bv.y;
      float gg = acc[mf][2][r] + bv.z;
      float go = acc[mf][3][r] + bv.w;
      float cn = fast_sigmoid(gf) * cold[r] + fast_sigmoid(gi) * fast_tanh(gg);
      cnew[r] = cn;
      lds[(rowl0 + r) * 64 + cgl] = f2bf(fast_sigmoid(go) * fast_tanh(cn));
    }
    *(f32x4*)&c1[(size_t)cg * NROWS + row0] = cnew;
  }
  __syncthreads();
#pragma unroll
  for (int itw = 0; itw < 4; ++itw) {
    int p = itw * 512 + tid;
    int row = p >> 3, ch = p & 7;
    *(u16x8*)(nxt_out + (size_t)(bm * 256 + row) * 1024 + 512 + bn * 64 + ch * 8) =
        *(const u16x8*)(lds + row * 64 + ch * 8);
  }
}

// S3: pos = relu(h1 @ Wfc1^T + bfc1) @ Wfc2^T + bfc2 ; write preds[:,t], posb.
__global__ __launch_bounds__(256) void k_s3(const unsigned short* __restrict__ H,
                                            const unsigned short* __restrict__ Wfc1b,
                                            const float* __restrict__ bfc1,
                                            const float* __restrict__ Wfc2,
                                            const float* __restrict__ bfc2,
                                            float* __restrict__ out, float* __restrict__ posb,
                                            int t) {
  __shared__ __align__(16) unsigned short ldsA[32 * 64];    // 4 KB
  __shared__ __align__(16) unsigned short ldsB[256 * 64];   // 32 KB
  __shared__ float wfc2s[512];
  __shared__ float red[32 * 8];                             // [row][wave*2+d]
  int tid = threadIdx.x;
  int l = blockIdx.x, xcd = l & 7, i = l >> 3;              // i in 0..87
  int b32 = 4 * (xcd + 8 * (i >> 2)) + (i & 3);             // 0..703
  wfc2s[tid] = Wfc2[tid];
  wfc2s[tid + 256] = Wfc2[tid + 256];
  int lane = tid & 63, wid = tid >> 6;                      // wid = wave col-group
  int c16 = lane & 15, q = lane >> 4;
  f32x4 acc[2][4];
#pragma unroll
  for (int ii = 0; ii < 2; ++ii)
#pragma unroll
    for (int jj = 0; jj < 4; ++jj) acc[ii][jj] = f32x4{0.f, 0.f, 0.f, 0.f};
  const unsigned short* Ab = H + (size_t)b32 * 32 * 1024 + 512;
#pragma unroll
  for (int kt = 0; kt < 8; ++kt) {
    int k0 = kt * 64;
    __syncthreads();
    {
      int p = tid;                                          // 256 slots: 32 rows x 8 chunks
      int row = p >> 3, u = p & 7, ch = u ^ (row & 7);
      async_copy16(Ab + row * 1024 + k0 + ch * 8, ldsA + p * 8);
    }
#pragma unroll
    for (int rd = 0; rd < 8; ++rd) {
      int p = rd * 256 + tid;
      int row = p >> 3, u = p & 7, ch = u ^ (row & 7);
      async_copy16(Wfc1b + row * 512 + k0 + ch * 8, ldsB + p * 8);
    }
    __syncthreads();
#pragma unroll
    for (int s = 0; s < 2; ++s) {
      bf16x8 a[2], b[4];
#pragma unroll
      for (int mf = 0; mf < 2; ++mf) {
        int row = mf * 16 + c16;
        int slot = row * 8 + ((s * 4 + q) ^ (row & 7));
        a[mf] = *(const bf16x8*)(ldsA + slot * 8);
      }
#pragma unroll
      for (int nf = 0; nf < 4; ++nf) {
        int row = wid * 64 + nf * 16 + c16;
        int slot = row * 8 + ((s * 4 + q) ^ (row & 7));
        b[nf] = *(const bf16x8*)(ldsB + slot * 8);
      }
#pragma unroll
      for (int mf = 0; mf < 2; ++mf)
#pragma unroll
        for (int nf = 0; nf < 4; ++nf)
          acc[mf][nf] = __builtin_amdgcn_mfma_f32_16x16x32_bf16(a[mf], b[nf], acc[mf][nf], 0, 0, 0);
    }
  }
  float part[2][2][4];   // [d][mf][r]
#pragma unroll
  for (int d = 0; d < 2; ++d)
#pragma unroll
    for (int mf = 0; mf < 2; ++mf)
#pragma unroll
      for (int r = 0; r < 4; ++r) part[d][mf][r] = 0.f;
#pragma unroll
  for (int nf = 0; nf < 4; ++nf) {
    int col = wid * 64 + nf * 16 + c16;
    float w0 = wfc2s[col], w1 = wfc2s[256 + col], bv = bfc1[col];
#pragma unroll
    for (int mf = 0; mf < 2; ++mf)
#pragma unroll
      for (int r = 0; r < 4; ++r) {
        float v = acc[mf][nf][r] + bv;
        v = v > 0.f ? v : 0.f;
        part[0][mf][r] += v * w0;
        part[1][mf][r] += v * w1;
      }
  }
#pragma unroll
  for (int st = 1; st < 16; st <<= 1)
#pragma unroll
    for (int d = 0; d < 2; ++d)
#pragma unroll
      for (int mf = 0; mf < 2; ++mf)
#pragma unroll
        for (int r = 0; r < 4; ++r)
          part[d][mf][r] += __shfl_xor(part[d][mf][r], st, 64);
  if (c16 == 0) {
#pragma unroll
    for (int mf = 0; mf < 2; ++mf)
#pragma unroll
      for (int r = 0; r < 4; ++r) {
        int rl = mf * 16 + q * 4 + r;                      // 0..31
        red[rl * 8 + wid * 2 + 0] = part[0][mf][r];
        red[rl * 8 + wid * 2 + 1] = part[1][mf][r];
      }
  }
  __syncthreads();
  if (tid < 64) {
    int rl = tid >> 1, d = tid & 1;
    float s = red[rl * 8 + d] + red[rl * 8 + 2 + d] + red[rl * 8 + 4 + d]
            + red[rl * 8 + 6 + d] + bfc2[d];
    int rg = b32 * 32 + rl;
    out[((size_t)rg * T_STEPS + t) * 2 + d] = s;
    posb[rg * 2 + d] = s;
  }
}

// ---------------- launch ----------------
extern "C" void kernel_launch(void* const* d_in, const int* in_sizes, int n_in,
                              void* d_out, int out_size, void* d_ws, size_t ws_size,
                              hipStream_t stream) {
  (void)in_sizes; (void)n_in; (void)out_size;
  const float* ctx   = (const float*)d_in[0];
  const float* pos0  = (const float*)d_in[1];
  const float* ball  = (const float*)d_in[2];
  const int*   roles = (const int*)d_in[3];
  const float* role_table = (const float*)d_in[5];
  const float* Wih0 = (const float*)d_in[6];
  const float* Whh0 = (const float*)d_in[7];
  const float* b0   = (const float*)d_in[8];
  const float* Wih1 = (const float*)d_in[9];
  const float* Whh1 = (const float*)d_in[10];
  const float* b1   = (const float*)d_in[11];
  const float* Wfc1 = (const float*)d_in[12];
  const float* bfc1 = (const float*)d_in[13];
  const float* Wfc2 = (const float*)d_in[14];
  const float* bfc2 = (const float*)d_in[15];
  const float* Winit = (const float*)d_in[16];
  const float* binit = (const float*)d_in[17];
  float* out = (float*)d_out;

  char* w = (char*)d_ws;
  size_t used = 0;
  auto alloc = [&](size_t bytes) {
    char* p = w + used;
    used += (bytes + 255) & ~(size_t)255;
    return p;
  };
  unsigned short* W0p   = (unsigned short*)alloc((size_t)2048 * 512 * 2);
  unsigned short* Wc1p  = (unsigned short*)alloc((size_t)2048 * 1024 * 2);
  unsigned short* Wfc1b = (unsigned short*)alloc((size_t)256 * 512 * 2);
  float* Wposx = (float*)alloc(2048 * 4);
  float* Wposy = (float*)alloc(2048 * 4);
  float* b0p4  = (float*)alloc(2048 * 4);
  float* b1p4  = (float*)alloc(2048 * 4);
  float* posb  = (float*)alloc((size_t)NROWS * 2 * 4);
  unsigned short* Hc0 = (unsigned short*)alloc((size_t)NROWS * 1024 * 2);
  float* c0   = (float*)alloc((size_t)NROWS * 512 * 4);
  float* c1   = (float*)alloc((size_t)NROWS * 512 * 4);
  unsigned short* Hc1 = (unsigned short*)alloc((size_t)NROWS * 1024 * 2);

  const size_t SP_BYTES = (size_t)NROWS * 2048 * 2;           // 92.3 MB
  const bool use_sp = (ws_size >= used + SP_BYTES + (1u << 20));

  unsigned short *Xs, *Wsp, *SP2;
  if (use_sp) {
    SP2 = (unsigned short*)alloc(SP_BYTES);
    Xs  = Hc1;                                 // transient: dead before Hc1 is written
    Wsp = Hc1 + (size_t)NROWS * 384;
  } else {
    SP2 = Hc1;                                 // never dereferenced on lite path
    Xs  = (unsigned short*)alloc((size_t)NROWS * 384 * 2);
    Wsp = (unsigned short*)alloc((size_t)2048 * 384 * 2);
  }

  k_prep_w<<<2048, 512, 0, stream>>>(Whh0, Wih1, Whh1, Wih0, Wfc1, b0, b1,
                                     W0p, Wc1p, Wsp, Wfc1b, Wposx, Wposy, b0p4, b1p4);
  k_init_xs<<<NROWS, 384, 0, stream>>>(ball, ctx, roles, role_table, Xs);
  k_init_state<<<(NROWS * 512 + 255) / 256, 256, 0, stream>>>(pos0, Winit, binit, Hc0, c0, c1, posb);

  if (use_sp) {
    dim3 gs(16, NBM);
    k_static<<<gs, 256, 0, stream>>>(Xs, Wsp, b0p4, SP2);
  }

  for (int t = 0; t < T_STEPS; ++t) {
    unsigned short* cur = (t & 1) ? Hc1 : Hc0;
    unsigned short* nxt = (t & 1) ? Hc0 : Hc1;
    if (use_sp)
      k_s1_8<true><<<704, 512, 0, stream>>>(cur, Xs, W0p, Wsp, SP2, b0p4,
                                            Wposx, Wposy, posb, c0, nxt);
    else
      k_s1_8<false><<<704, 512, 0, stream>>>(cur, Xs, W0p, Wsp, SP2, b0p4,
                                             Wposx, Wposy, posb, c0, nxt);
    k_s2_8<<<704, 512, 0, stream>>>(nxt, cur, Wc1p, b1p4, c1, nxt);
    k_s3<<<704, 256, 0, stream>>>(nxt, Wfc1b, bfc1, Wfc2, bfc2, out, posb, t);
  }
}

// Round 7
// 21523.598 us; speedup vs baseline: 3.3213x; 1.0305x over previous
//
#include <hip/hip_runtime.h>
#include <cstdint>

// RoleConditionedLSTMDecoder on MI355X (gfx950) — R15.
// KEY INSIGHT: the recurrence is ROW-LOCAL (no cross-row coupling anywhere).
// So: ONE PERSISTENT KERNEL, 256 blocks x 512 thr, block b owns rows
// [b*88, +88) (padded to 96 for 16-row MFMA frags) for ALL 100 steps.
// Zero dispatch boundaries, zero cross-block sync (legal: blocks fully
// independent), h/c state served by own-XCD L2 (same-CU store->load
// coherence is architectural), weights (6.25MB) streamed L2/L3 -> LDS.
// Per step per block: GEMM1 (96x2048x512) + cell0, GEMM2 (96x2048x1024,
// A=[h0|h1]) + cell1, MLP (96x256x512) + out. K-loop = R10-style ledger:
// gload_lds staging (A chunks K=128 3 loads/thr, B chunks K=64 4 loads/thr,
// double-buffered, XOR bank layouts), counted vmcnt (7/4/0), 2 raw
// s_barrier per K64 iter, setprio around MFMA, sched_barrier(0) seal.
// Accumulation order identical to R10 -> absmax must be EXACTLY 0.007354736.
// Old R14 3-dispatch path retained as lite fallback (ws too small).

#define DEVI __device__ __forceinline__

typedef __bf16 bf16x8 __attribute__((ext_vector_type(8)));
typedef float  f32x4  __attribute__((ext_vector_type(4)));
typedef float  f32x2  __attribute__((ext_vector_type(2)));
typedef unsigned short u16x4 __attribute__((ext_vector_type(4)));
typedef unsigned short u16x8 __attribute__((ext_vector_type(8)));

static constexpr int NROWS = 22528;    // B*P
static constexpr int NROWSP = 22536;   // +8 pad rows (256 blocks x 88 + 8)
static constexpr int T_STEPS = 100;
static constexpr int NBM = 176;        // 22528/128 row-tiles (k_static only)

DEVI unsigned short f2bf(float f) {
  unsigned u = __float_as_uint(f);
  u = u + 0x7FFFu + ((u >> 16) & 1u);   // RNE
  return (unsigned short)(u >> 16);
}
DEVI float bf2f(unsigned short h) { return __uint_as_float(((unsigned)h) << 16); }

DEVI float fast_sigmoid(float x) {
  float e = __builtin_amdgcn_exp2f(-1.442695041f * x);
  return __builtin_amdgcn_rcpf(1.0f + e);
}
DEVI float fast_tanh(float x) {
  float e = __builtin_amdgcn_exp2f(2.885390082f * x);   // e^(2x)
  return 1.0f - 2.0f * __builtin_amdgcn_rcpf(e + 1.0f);
}

DEVI void async_copy16(const void* g, void* l) {
  __builtin_amdgcn_global_load_lds(
      (const __attribute__((address_space(1))) void*)g,
      (__attribute__((address_space(3))) void*)l, 16, 0, 0);
}

#define GBAR   asm volatile("s_barrier" ::: "memory")

// ---------------- 128x128 GEMM core (k_static only) — proven ----------------
template <int KITERS, int KSWITCH>
DEVI void gemm_core(const unsigned short* __restrict__ A1, int lda1,
                    const unsigned short* __restrict__ A2, int lda2,
                    const unsigned short* __restrict__ B1, int ldb1,
                    const unsigned short* __restrict__ B2, int ldb2,
                    unsigned short* lds, f32x4 acc[4][4], int tid) {
  const int lane = tid & 63, wid = tid >> 6;
  const int wm = wid & 1, wn = wid >> 1;
  const int c16 = lane & 15, q = lane >> 4;
#pragma unroll
  for (int i = 0; i < 4; ++i)
#pragma unroll
    for (int j = 0; j < 4; ++j) acc[i][j] = f32x4{0.f, 0.f, 0.f, 0.f};
#pragma unroll
  for (int kt = 0; kt < KITERS; ++kt) {
    const bool sec = (kt >= KSWITCH);
    const unsigned short* Ab = sec ? A2 : A1;
    const unsigned short* Bb = sec ? B2 : B1;
    const int lda = sec ? lda2 : lda1;
    const int ldb = sec ? ldb2 : ldb1;
    const int kk = (sec ? (kt - KSWITCH) : kt) * 64;
    __syncthreads();
#pragma unroll
    for (int rd = 0; rd < 4; ++rd) {
      int p = rd * 256 + tid;
      int row = p >> 3, u = p & 7, ch = u ^ (row & 7);
      async_copy16(Ab + row * lda + kk + ch * 8, lds + p * 8);
      async_copy16(Bb + row * ldb + kk + ch * 8, lds + 8192 + p * 8);
    }
    __syncthreads();
#pragma unroll
    for (int s = 0; s < 2; ++s) {
      bf16x8 a[4], b[4];
#pragma unroll
      for (int mf = 0; mf < 4; ++mf) {
        int row = wm * 64 + mf * 16 + c16;
        int slot = row * 8 + ((s * 4 + q) ^ (row & 7));
        a[mf] = *(const bf16x8*)(lds + slot * 8);
      }
#pragma unroll
      for (int nf = 0; nf < 4; ++nf) {
        int row = wn * 64 + nf * 16 + c16;
        int slot = row * 8 + ((s * 4 + q) ^ (row & 7));
        b[nf] = *(const bf16x8*)(lds + 8192 + slot * 8);
      }
#pragma unroll
      for (int mf = 0; mf < 4; ++mf)
#pragma unroll
        for (int nf = 0; nf < 4; ++nf)
          acc[mf][nf] = __builtin_amdgcn_mfma_f32_16x16x32_bf16(a[mf], b[nf], acc[mf][nf], 0, 0, 0);
    }
  }
}

// ---------------- prep ----------------
DEVI int orig_row(int j) {
  int tile = j >> 7, rem = j & 127;
  int half = rem >> 6, g = (rem >> 4) & 3, cc = rem & 15;
  return g * 512 + (tile * 32 + half * 16 + cc);
}

__global__ void k_prep_w(const float* __restrict__ Whh0, const float* __restrict__ Wih1,
                         const float* __restrict__ Whh1, const float* __restrict__ Wih0,
                         const float* __restrict__ Wfc1, const float* __restrict__ b0,
                         const float* __restrict__ b1,
                         unsigned short* __restrict__ W0p, unsigned short* __restrict__ Wc1p,
                         unsigned short* __restrict__ Wsp, unsigned short* __restrict__ Wfc1b,
                         float* __restrict__ Wposx, float* __restrict__ Wposy,
                         float* __restrict__ b0p4, float* __restrict__ b1p4) {
  int j = blockIdx.x;       // 0..2047
  int k = threadIdx.x;      // 0..511
  int o = orig_row(j);
  W0p[j * 512 + k]         = f2bf(Whh0[o * 512 + k]);
  Wc1p[j * 1024 + k]       = f2bf(Wih1[o * 512 + k]);
  Wc1p[j * 1024 + 512 + k] = f2bf(Whh1[o * 512 + k]);
  if (k < 384) Wsp[j * 384 + k] = (k < 322) ? f2bf(Wih0[o * 324 + 2 + k]) : (unsigned short)0;
  if (k == 0) {
    int g = (j >> 4) & 3;
    int cg = (j >> 7) * 32 + ((j >> 6) & 1) * 16 + (j & 15);
    Wposx[cg * 4 + g] = Wih0[o * 324 + 0];
    Wposy[cg * 4 + g] = Wih0[o * 324 + 1];
    b0p4[cg * 4 + g] = b0[o];
    b1p4[cg * 4 + g] = b1[o];
  }
  if (j < 256) Wfc1b[j * 512 + k] = f2bf(Wfc1[j * 512 + k]);
}

__global__ void k_init_xs(const float* __restrict__ ball, const float* __restrict__ ctx,
                          const int* __restrict__ roles, const float* __restrict__ role_table,
                          unsigned short* __restrict__ Xs) {
  int n = blockIdx.x, col = threadIdx.x;  // 22528 x 384
  int b = n / 22;
  float v;
  if (col < 2)        v = ball[b * 2 + col];
  else if (col < 258) v = ctx[(size_t)n * 256 + col - 2];
  else if (col < 322) v = role_table[roles[n] * 64 + col - 258];
  else                v = 0.f;
  Xs[(size_t)n * 384 + col] = f2bf(v);
}

// persistent-path init: h0A/h1A [row][512], c0/c1 zero (size 512*NROWSP),
// posb, SP2 pad rows zeroed.
__global__ void k_init_p(const float* __restrict__ pos0, const float* __restrict__ Winit,
                         const float* __restrict__ binit,
                         unsigned short* __restrict__ h0A, unsigned short* __restrict__ h1A,
                         float* __restrict__ c0, float* __restrict__ c1,
                         float* __restrict__ posb, unsigned short* __restrict__ SP2) {
  int idx = blockIdx.x * 256 + threadIdx.x;     // NROWSP*512
  if (idx >= NROWSP * 512) return;
  int n = idx >> 9, c = idx & 511;
  if (n < NROWS) {
    float px = pos0[n * 2 + 0], py = pos0[n * 2 + 1];
    h0A[(size_t)n * 512 + c] = f2bf(binit[c] + Winit[c * 2 + 0] * px + Winit[c * 2 + 1] * py);
    if (c < 2) posb[n * 2 + c] = pos0[n * 2 + c];
  } else {
    h0A[(size_t)n * 512 + c] = 0;
    if (c < 2) posb[n * 2 + c] = 0.f;
    ((unsigned long long*)SP2)[(size_t)n * 512 + c] = 0ull;   // zero pad SP2 row
  }
  h1A[(size_t)n * 512 + c] = 0;
  c0[idx] = 0.f;                                // layout-agnostic zero fill
  c1[idx] = 0.f;
}

// old-path init (lite fallback): Hcat concat layout
__global__ void k_init_state(const float* __restrict__ pos0, const float* __restrict__ Winit,
                             const float* __restrict__ binit, unsigned short* __restrict__ Hcat,
                             float* __restrict__ c0, float* __restrict__ c1,
                             float* __restrict__ posb) {
  int idx = blockIdx.x * 256 + threadIdx.x;     // N*512
  if (idx >= NROWS * 512) return;
  int n = idx >> 9, c = idx & 511;
  float px = pos0[n * 2 + 0], py = pos0[n * 2 + 1];
  float h0 = binit[c] + Winit[c * 2 + 0] * px + Winit[c * 2 + 1] * py;
  Hcat[(size_t)n * 1024 + c] = f2bf(h0);
  Hcat[(size_t)n * 1024 + 512 + c] = 0;
  c0[idx] = 0.f;
  c1[idx] = 0.f;
  if (c < 2) posb[n * 2 + c] = pos0[n * 2 + c];
}

// static_proj packed: SP2[row*512+cg] = ushort4{i,f,g,o} + b0
__global__ __launch_bounds__(256) void k_static(const unsigned short* __restrict__ Xs,
                                                const unsigned short* __restrict__ Wsp,
                                                const float* __restrict__ b0p4,
                                                unsigned short* __restrict__ SP2) {
  __shared__ __align__(16) unsigned short lds[16384];
  int tid = threadIdx.x, bn = blockIdx.x, bm = blockIdx.y;
  f32x4 acc[4][4];
  const unsigned short* Ab = Xs + (size_t)bm * 128 * 384;
  const unsigned short* Bb = Wsp + (size_t)bn * 128 * 384;
  gemm_core<6, 6>(Ab, 384, Ab, 384, Bb, 384, Bb, 384, lds, acc, tid);
  int lane = tid & 63, wid = tid >> 6, wm = wid & 1, wn = wid >> 1;
  int c16 = lane & 15, q = lane >> 4;
  int cg = bn * 32 + wn * 16 + c16;
  f32x4 bb = *(const f32x4*)&b0p4[cg * 4];
#pragma unroll
  for (int mf = 0; mf < 4; ++mf) {
    int row0 = bm * 128 + wm * 64 + mf * 16 + q * 4;
#pragma unroll
    for (int r = 0; r < 4; ++r) {
      u16x4 v;
      v.x = f2bf(acc[mf][0][r] + bb.x);
      v.y = f2bf(acc[mf][1][r] + bb.y);
      v.z = f2bf(acc[mf][2][r] + bb.z);
      v.w = f2bf(acc[mf][3][r] + bb.w);
      ((u16x4*)SP2)[(size_t)(row0 + r) * 512 + cg] = v;
    }
  }
}

// ---------------- persistent GEMM core: 96 rows x 256 gate-cols ----------------
// A: row-major 512 elems/row (h buffers). B: j-major, ldb bytes/row.
// A chunks K=128 (3 loads/thr, granule pos = g ^ (row&7) -> 2-way banks).
// B chunks K=64 = 2 sub-chunks K=32 (R10 stage_q layout, 2-way banks).
// Ledger: wait N = loads issued this iter (7 even / 4 odd / 0 last).

DEVI void stageA_p(const unsigned short* As, int rowbase, int coff,
                   unsigned short* dst, int tid) {
#pragma unroll
  for (int rd = 0; rd < 3; ++rd) {
    int p = rd * 512 + tid;
    int row = p >> 4, gp = p & 15;
    async_copy16(As + (size_t)(rowbase + row) * 512 + coff + (gp ^ (row & 7)) * 8,
                 dst + p * 8);
  }
}

DEVI void stageB_p(const char* Bnt, int ldb, int koff, unsigned short* dst, int tid) {
#pragma unroll
  for (int ks = 0; ks < 2; ++ks)
#pragma unroll
    for (int rd = 0; rd < 2; ++rd) {
      int p = rd * 512 + tid;
      int j = p >> 2, u = p & 3, ch = u ^ ((j >> 1) & 3);
      async_copy16(Bnt + (size_t)j * ldb + koff + ks * 64 + ch * 16,
                   dst + ks * 8192 + p * 8);
    }
}

template <int KT, int KSW>   // KT = K/64 iters; A switches at kt==KSW (KSW even)
DEVI void gemm_p(const unsigned short* A1, const unsigned short* A2, int rowbase,
                 const char* Bnt, int ldb,
                 unsigned short* Abuf, unsigned short* Bbuf,
                 f32x4 acc[3][4], int tid) {
  const int lane = tid & 63, wid = tid >> 6;
  const int wm = wid >> 2, wn = wid & 3;
  const int c16 = lane & 15, q = lane >> 4;
#pragma unroll
  for (int i = 0; i < 3; ++i)
#pragma unroll
    for (int j = 0; j < 4; ++j) acc[i][j] = f32x4{0.f, 0.f, 0.f, 0.f};
  stageA_p(A1, rowbase, 0, Abuf, tid);
  stageB_p(Bnt, ldb, 0, Bbuf, tid);
#pragma unroll
  for (int kt = 0; kt < KT; ++kt) {
    GBAR;   // close previous iter's LDS reads before restaging
    int nIss = 0;
    if (kt + 1 < KT) { stageB_p(Bnt, ldb, (kt + 1) * 128, Bbuf + ((kt + 1) & 1) * 16384, tid); nIss += 4; }
    if ((kt & 1) == 0 && (kt / 2 + 1) < KT / 2) {
      int c = kt / 2 + 1;
      const unsigned short* As = (c < KSW / 2) ? A1 : A2;
      int coff = ((c < KSW / 2) ? c : (c - KSW / 2)) * 128;
      stageA_p(As, rowbase, coff, Abuf + (c & 1) * 12288, tid);
      nIss += 3;
    }
    if (nIss == 7)      asm volatile("s_waitcnt vmcnt(7)" ::: "memory");
    else if (nIss == 4) asm volatile("s_waitcnt vmcnt(4)" ::: "memory");
    else if (nIss == 3) asm volatile("s_waitcnt vmcnt(3)" ::: "memory");
    else                asm volatile("s_waitcnt vmcnt(0)" ::: "memory");
    GBAR;
    const unsigned short* Ab = Abuf + ((kt >> 1) & 1) * 12288;
    const unsigned short* Bb = Bbuf + (kt & 1) * 16384;
#pragma unroll
    for (int ks = 0; ks < 2; ++ks) {
      bf16x8 a[3], b[4];
#pragma unroll
      for (int mf = 0; mf < 3; ++mf) {
        int rl = wm * 48 + mf * 16 + c16;
        int g = (kt & 1) * 8 + ks * 4 + q;
        a[mf] = *(const bf16x8*)(Ab + rl * 128 + (g ^ (rl & 7)) * 8);
      }
#pragma unroll
      for (int nf = 0; nf < 4; ++nf) {
        int jl = wn * 64 + nf * 16 + c16;
        b[nf] = *(const bf16x8*)(Bb + ks * 8192 + (jl * 4 + (q ^ ((jl >> 1) & 3))) * 8);
      }
      __builtin_amdgcn_s_setprio(1);
#pragma unroll
      for (int mf = 0; mf < 3; ++mf)
#pragma unroll
        for (int nf = 0; nf < 4; ++nf)
          acc[mf][nf] = __builtin_amdgcn_mfma_f32_16x16x32_bf16(a[mf], b[nf], acc[mf][nf], 0, 0, 0);
      __builtin_amdgcn_s_setprio(0);
    }
    __builtin_amdgcn_sched_barrier(0);
  }
}

// ---------------- persistent kernel: all 100 steps, zero cross-block deps ----------------
__global__ __launch_bounds__(512, 2) void k_persist(
    const unsigned short* __restrict__ W0p, const unsigned short* __restrict__ Wc1p,
    const unsigned short* __restrict__ Wfc1b, const unsigned short* __restrict__ SP2,
    const float* __restrict__ b1p4,
    const float* __restrict__ Wposx, const float* __restrict__ Wposy,
    const float* __restrict__ bfc1, const float* __restrict__ Wfc2,
    const float* __restrict__ bfc2,
    unsigned short* __restrict__ h0A, unsigned short* __restrict__ h0B,
    unsigned short* __restrict__ h1A, unsigned short* __restrict__ h1B,
    float* __restrict__ c0, float* __restrict__ c1,
    float* __restrict__ posb, float* __restrict__ out) {
  __shared__ __align__(16) unsigned short Abuf[2 * 12288];   // 48 KB
  __shared__ __align__(16) unsigned short Bbuf[2 * 16384];   // 64 KB
  __shared__ float wfc2s[512];
  __shared__ float red[96 * 8];
  const int tid = threadIdx.x, blk = blockIdx.x;
  const int lane = tid & 63, wid = tid >> 6;
  const int wm = wid >> 2, wn = wid & 3;
  const int c16 = lane & 15, q = lane >> 4;
  const int rowbase = blk * 88;
  wfc2s[tid] = Wfc2[tid];               // tid 0..511 covers 512
  __syncthreads();
  f32x4 acc[3][4];
#pragma unroll 1
  for (int t = 0; t < T_STEPS; ++t) {
    const unsigned short* h0p = (t & 1) ? h0B : h0A;
    unsigned short*       h0n = (t & 1) ? h0A : h0B;
    const unsigned short* h1p = (t & 1) ? h1B : h1A;
    unsigned short*       h1n = (t & 1) ? h1A : h1B;
    // ---- phase A: layer0 ----
#pragma unroll 1
    for (int nt = 0; nt < 8; ++nt) {
      gemm_p<8, 8>(h0p, h0p, rowbase, (const char*)W0p + (size_t)nt * 256 * 1024, 1024,
                   Abuf, Bbuf, acc, tid);
      const int cg = nt * 64 + (wn >> 1) * 32 + (wn & 1) * 16 + c16;
      f32x4 wpx = *(const f32x4*)&Wposx[cg * 4];
      f32x4 wpy = *(const f32x4*)&Wposy[cg * 4];
#pragma unroll
      for (int mf = 0; mf < 3; ++mf) {
        int row0 = rowbase + wm * 48 + mf * 16 + q * 4;
        f32x4 cold = *(const f32x4*)&c0[(size_t)cg * NROWSP + row0];
        f32x4 cnew;
#pragma unroll
        for (int r = 0; r < 4; ++r) {
          size_t row = row0 + r;
          f32x2 pv = *(const f32x2*)&posb[row * 2];
          u16x4 sp = ((const u16x4*)SP2)[row * 512 + cg];
          float gi = acc[mf][0][r] + bf2f(sp.x) + pv.x * wpx.x + pv.y * wpy.x;
          float gf = acc[mf][1][r] + bf2f(sp.y) + pv.x * wpx.y + pv.y * wpy.y;
          float gg = acc[mf][2][r] + bf2f(sp.z) + pv.x * wpx.z + pv.y * wpy.z;
          float go = acc[mf][3][r] + bf2f(sp.w) + pv.x * wpx.w + pv.y * wpy.w;
          float cn = fast_sigmoid(gf) * cold[r] + fast_sigmoid(gi) * fast_tanh(gg);
          cnew[r] = cn;
          h0n[row * 512 + cg] = f2bf(fast_sigmoid(go) * fast_tanh(cn));
        }
        *(f32x4*)&c0[(size_t)cg * NROWSP + row0] = cnew;
      }
      __syncthreads();   // drain stores + close LDS before next nt restage
    }
    // ---- phase B: layer1 (A = [h0n | h1p], K=1024) ----
#pragma unroll 1
    for (int nt = 0; nt < 8; ++nt) {
      gemm_p<16, 8>(h0n, h1p, rowbase, (const char*)Wc1p + (size_t)nt * 256 * 2048, 2048,
                    Abuf, Bbuf, acc, tid);
      const int cg = nt * 64 + (wn >> 1) * 32 + (wn & 1) * 16 + c16;
      f32x4 bv = *(const f32x4*)&b1p4[cg * 4];
#pragma unroll
      for (int mf = 0; mf < 3; ++mf) {
        int row0 = rowbase + wm * 48 + mf * 16 + q * 4;
        f32x4 cold = *(const f32x4*)&c1[(size_t)cg * NROWSP + row0];
        f32x4 cnew;
#pragma unroll
        for (int r = 0; r < 4; ++r) {
          size_t row = row0 + r;
          float gi = acc[mf][0][r] + bv.x;
          float gf = acc[mf][1][r] + bv.y;
          float gg = acc[mf][2][r] + bv.z;
          float go = acc[mf][3][r] + bv.w;
          float cn = fast_sigmoid(gf) * cold[r] + fast_sigmoid(gi) * fast_tanh(gg);
          cnew[r] = cn;
          h1n[row * 512 + cg] = f2bf(fast_sigmoid(go) * fast_tanh(cn));
        }
        *(f32x4*)&c1[(size_t)cg * NROWSP + row0] = cnew;
      }
      __syncthreads();
    }
    // ---- phase C: MLP + out + posb ----
    {
      gemm_p<8, 8>(h1n, h1n, rowbase, (const char*)Wfc1b, 1024, Abuf, Bbuf, acc, tid);
      float part[2][3][4];
#pragma unroll
      for (int d = 0; d < 2; ++d)
#pragma unroll
        for (int mf = 0; mf < 3; ++mf)
#pragma unroll
          for (int r = 0; r < 4; ++r) part[d][mf][r] = 0.f;
#pragma unroll
      for (int nf = 0; nf < 4; ++nf) {
        int col = wn * 64 + nf * 16 + c16;
        float w0 = wfc2s[col], w1 = wfc2s[256 + col], bv = bfc1[col];
#pragma unroll
        for (int mf = 0; mf < 3; ++mf)
#pragma unroll
          for (int r = 0; r < 4; ++r) {
            float v = acc[mf][nf][r] + bv;
            v = v > 0.f ? v : 0.f;
            part[0][mf][r] += v * w0;
            part[1][mf][r] += v * w1;
          }
      }
#pragma unroll
      for (int st = 1; st < 16; st <<= 1)
#pragma unroll
        for (int d = 0; d < 2; ++d)
#pragma unroll
          for (int mf = 0; mf < 3; ++mf)
#pragma unroll
            for (int r = 0; r < 4; ++r)
              part[d][mf][r] += __shfl_xor(part[d][mf][r], st, 64);
      if (c16 == 0) {
#pragma unroll
        for (int mf = 0; mf < 3; ++mf)
#pragma unroll
          for (int r = 0; r < 4; ++r) {
            int rl = wm * 48 + mf * 16 + q * 4 + r;
            red[rl * 8 + wn * 2 + 0] = part[0][mf][r];
            red[rl * 8 + wn * 2 + 1] = part[1][mf][r];
          }
      }
      __syncthreads();
      if (tid < 192) {
        int rl = tid >> 1, d = tid & 1;
        float s = red[rl * 8 + d] + red[rl * 8 + 2 + d] + red[rl * 8 + 4 + d]
                + red[rl * 8 + 6 + d] + bfc2[d];
        if (rl < 88) {
          int rg = rowbase + rl;
          out[((size_t)rg * T_STEPS + t) * 2 + d] = s;
          posb[rg * 2 + d] = s;
        }
      }
      __syncthreads();   // posb/red settled before next step reads
    }
  }
}

// ---------------- lite-fallback per-step kernels (R14, proven) ----------------
struct GemmSrc {
  const unsigned short *A1, *A2, *B1, *B2;
  int ldA1, ldA2, ldB1, ldB2;
};

template <int KT, int KSW>
DEVI void stage_q(const GemmSrc& g, int t, int s, int isB, unsigned short* dst, int tid) {
  int tt = (t >= KT) ? (t - 2) : t;
  const bool sec = (tt >= KSW);
  const unsigned short* base;
  int ld;
  if (isB) { base = sec ? g.B2 : g.B1; ld = sec ? g.ldB2 : g.ldB1; }
  else     { base = sec ? g.A2 : g.A1; ld = sec ? g.ldA2 : g.ldA1; }
  base += (sec ? (tt - KSW) : tt) * 64 + s * 32;
#pragma unroll
  for (int rd = 0; rd < 2; ++rd) {
    int p = rd * 512 + tid;
    int row = p >> 2, u = p & 3, ch = u ^ ((row >> 1) & 3);
    async_copy16(base + row * ld + ch * 8, dst + p * 8);
  }
}

#define VMCNT4 asm volatile("s_waitcnt vmcnt(4)" ::: "memory")

template <int KT, int KSW>
DEVI void gemm8(const GemmSrc& g, unsigned short* lds, f32x4 acc[8][4], int tid) {
  const int lane = tid & 63, wid = tid >> 6;
  const int wm = wid >> 2, wn = wid & 3;
  const int c16 = lane & 15, q = lane >> 4;
#pragma unroll
  for (int i = 0; i < 8; ++i)
#pragma unroll
    for (int j = 0; j < 4; ++j) acc[i][j] = f32x4{0.f, 0.f, 0.f, 0.f};
  unsigned short* A00 = lds;
  unsigned short* A01 = lds + 8192;
  unsigned short* B00 = lds + 16384;
  unsigned short* B01 = lds + 24576;
  unsigned short* A10 = lds + 32768;
  unsigned short* A11 = lds + 40960;
  unsigned short* B10 = lds + 49152;
  unsigned short* B11 = lds + 57344;
  const int rowA0 = wm * 128 + c16;
  const int rowB0 = wn * 64 + c16;
  stage_q<KT, KSW>(g, 0, 0, 0, A00, tid);
  stage_q<KT, KSW>(g, 0, 0, 1, B00, tid);
  stage_q<KT, KSW>(g, 0, 1, 0, A01, tid);
  stage_q<KT, KSW>(g, 0, 1, 1, B01, tid);
  stage_q<KT, KSW>(g, 1, 0, 0, A10, tid);
  stage_q<KT, KSW>(g, 1, 0, 1, B10, tid);
  VMCNT4;
  GBAR;
  bf16x8 a[4], b[4];
#define LOADA(BASE, MG)                                                        \
  _Pragma("unroll")                                                            \
  for (int f = 0; f < 4; ++f) {                                                \
    int row = rowA0 + ((MG) * 4 + f) * 16;                                     \
    a[f] = *(const bf16x8*)((BASE) + (row * 4 + (q ^ ((row >> 1) & 3))) * 8);  \
  }
#define LOADB(BASE)                                                            \
  _Pragma("unroll")                                                            \
  for (int f = 0; f < 4; ++f) {                                                \
    int row = rowB0 + f * 16;                                                  \
    b[f] = *(const bf16x8*)((BASE) + (row * 4 + (q ^ ((row >> 1) & 3))) * 8);  \
  }
#define MFG(MG)                                                                \
  __builtin_amdgcn_s_setprio(1);                                               \
  _Pragma("unroll")                                                            \
  for (int f = 0; f < 4; ++f)                                                  \
    _Pragma("unroll")                                                          \
    for (int nf = 0; nf < 4; ++nf)                                             \
      acc[(MG) * 4 + f][nf] = __builtin_amdgcn_mfma_f32_16x16x32_bf16(         \
          a[f], b[nf], acc[(MG) * 4 + f][nf], 0, 0, 0);                        \
  __builtin_amdgcn_s_setprio(0);                                               \
  __builtin_amdgcn_sched_barrier(0);
#pragma unroll 1
  for (int it = 0; it < KT / 2; ++it) {
    const int t0 = 2 * it;
    LOADA(A00, 0); LOADB(B00);
    stage_q<KT, KSW>(g, t0 + 1, 1, 0, A11, tid);
    GBAR; MFG(0); GBAR;
    LOADA(A00, 1);
    stage_q<KT, KSW>(g, t0 + 1, 1, 1, B11, tid);
    GBAR; MFG(1); GBAR;
    LOADA(A01, 0); LOADB(B01);
    stage_q<KT, KSW>(g, t0 + 2, 0, 0, A00, tid);
    GBAR; MFG(0); GBAR;
    LOADA(A01, 1);
    stage_q<KT, KSW>(g, t0 + 2, 0, 1, B00, tid);
    GBAR; MFG(1); VMCNT4; GBAR;
    LOADA(A10, 0); LOADB(B10);
    stage_q<KT, KSW>(g, t0 + 2, 1, 0, A01, tid);
    GBAR; MFG(0); GBAR;
    LOADA(A10, 1);
    stage_q<KT, KSW>(g, t0 + 2, 1, 1, B01, tid);
    GBAR; MFG(1); GBAR;
    LOADA(A11, 0); LOADB(B11);
    stage_q<KT, KSW>(g, t0 + 3, 0, 0, A10, tid);
    GBAR; MFG(0); GBAR;
    LOADA(A11, 1);
    stage_q<KT, KSW>(g, t0 + 3, 0, 1, B10, tid);
    GBAR; MFG(1); VMCNT4; GBAR;
  }
  asm volatile("s_waitcnt vmcnt(0)" ::: "memory");
#undef LOADA
#undef LOADB
#undef MFG
}

DEVI void swz704(int l, int& bn, int& bm) {
  int xcd = l & 7, ii = l >> 3;
  bn = ii & 7;
  bm = (ii >> 3) * 8 + xcd;
}

__global__ __launch_bounds__(512, 2) void k_s1_lite(const unsigned short* __restrict__ cur,
                                                    const unsigned short* __restrict__ Xs,
                                                    const unsigned short* __restrict__ W0p,
                                                    const unsigned short* __restrict__ Wsp,
                                                    const float* __restrict__ b0p4,
                                                    const float* __restrict__ Wposx,
                                                    const float* __restrict__ Wposy,
                                                    const float* __restrict__ posb,
                                                    float* __restrict__ c0,
                                                    unsigned short* __restrict__ nxt) {
  __shared__ __align__(16) unsigned short lds[65536];
  const int tid = threadIdx.x;
  int bn, bm;
  swz704(blockIdx.x, bn, bm);
  f32x4 acc[8][4];
  GemmSrc g;
  g.A1 = cur + (size_t)bm * 256 * 1024; g.ldA1 = 1024;
  g.B1 = W0p + (size_t)bn * 256 * 512;  g.ldB1 = 512;
  g.A2 = Xs + (size_t)bm * 256 * 384;   g.ldA2 = 384;
  g.B2 = Wsp + (size_t)bn * 256 * 384;  g.ldB2 = 384;
  gemm8<14, 8>(g, lds, acc, tid);
  const int lane = tid & 63, wid = tid >> 6;
  const int wm = wid >> 2, wn = wid & 3;
  const int c16 = lane & 15, q = lane >> 4;
  const int cg = bn * 64 + (wn >> 1) * 32 + (wn & 1) * 16 + c16;
  f32x4 wpx = *(const f32x4*)&Wposx[cg * 4];
  f32x4 wpy = *(const f32x4*)&Wposy[cg * 4];
  f32x4 sb = *(const f32x4*)&b0p4[cg * 4];
#pragma unroll
  for (int mf = 0; mf < 8; ++mf) {
    int row0 = bm * 256 + wm * 128 + mf * 16 + q * 4;
    f32x4 cold = *(const f32x4*)&c0[(size_t)cg * NROWS + row0];
    f32x4 cnew;
#pragma unroll
    for (int r = 0; r < 4; ++r) {
      size_t row = row0 + r;
      f32x2 pv = *(const f32x2*)&posb[row * 2];
      float gi = acc[mf][0][r] + sb.x + pv.x * wpx.x + pv.y * wpy.x;
      float gf = acc[mf][1][r] + sb.y + pv.x * wpx.y + pv.y * wpy.y;
      float gg = acc[mf][2][r] + sb.z + pv.x * wpx.z + pv.y * wpy.z;
      float go = acc[mf][3][r] + sb.w + pv.x * wpx.w + pv.y * wpy.w;
      float cn = fast_sigmoid(gf) * cold[r] + fast_sigmoid(gi) * fast_tanh(gg);
      cnew[r] = cn;
      nxt[row * 1024 + cg] = f2bf(fast_sigmoid(go) * fast_tanh(cn));
    }
    *(f32x4*)&c0[(size_t)cg * NROWS + row0] = cnew;
  }
}

__global__ __launch_bounds__(512, 2) void k_s2_8(const unsigned short* __restrict__ nxt_in,
                                                 const unsigned short* __restrict__ cur,
                                                 const unsigned short* __restrict__ Wc1p,
                                                 const float* __restrict__ b1p4,
                                                 float* __restrict__ c1,
                                                 unsigned short* __restrict__ nxt_out) {
  __shared__ __align__(16) unsigned short lds[65536];
  const int tid = threadIdx.x;
  int bn, bm;
  swz704(blockIdx.x, bn, bm);
  f32x4 acc[8][4];
  GemmSrc g;
  g.A1 = nxt_in + (size_t)bm * 256 * 1024;      g.ldA1 = 1024;
  g.A2 = cur + (size_t)bm * 256 * 1024 + 512;   g.ldA2 = 1024;
  g.B1 = Wc1p + (size_t)bn * 256 * 1024;        g.ldB1 = 1024;
  g.B2 = g.B1 + 512;                            g.ldB2 = 1024;
  gemm8<16, 8>(g, lds, acc, tid);
  const int lane = tid & 63, wid = tid >> 6;
  const int wm = wid >> 2, wn = wid & 3;
  const int c16 = lane & 15, q = lane >> 4;
  const int cg = bn * 64 + (wn >> 1) * 32 + (wn & 1) * 16 + c16;
  f32x4 bv = *(const f32x4*)&b1p4[cg * 4];
#pragma unroll
  for (int mf = 0; mf < 8; ++mf) {
    int row0 = bm * 256 + wm * 128 + mf * 16 + q * 4;
    f32x4 cold = *(const f32x4*)&c1[(size_t)cg * NROWS + row0];
    f32x4 cnew;
#pragma unroll
    for (int r = 0; r < 4; ++r) {
      size_t row = row0 + r;
      float gi = acc[mf][0][r] + bv.x;
      float gf = acc[mf][1][r] + bv.y;
      float gg = acc[mf][2][r] + bv.z;
      float go = acc[mf][3][r] + bv.w;
      float cn = fast_sigmoid(gf) * cold[r] + fast_sigmoid(gi) * fast_tanh(gg);
      cnew[r] = cn;
      nxt_out[row * 1024 + 512 + cg] = f2bf(fast_sigmoid(go) * fast_tanh(cn));
    }
    *(f32x4*)&c1[(size_t)cg * NROWS + row0] = cnew;
  }
}

__global__ __launch_bounds__(256) void k_s3(const unsigned short* __restrict__ H,
                                            const unsigned short* __restrict__ Wfc1b,
                                            const float* __restrict__ bfc1,
                                            const float* __restrict__ Wfc2,
                                            const float* __restrict__ bfc2,
                                            float* __restrict__ out, float* __restrict__ posb,
                                            int t) {
  __shared__ __align__(16) unsigned short ldsA[32 * 64];
  __shared__ __align__(16) unsigned short ldsB[256 * 64];
  __shared__ float wfc2s[512];
  __shared__ float red[32 * 8];
  int tid = threadIdx.x;
  int l = blockIdx.x, xcd = l & 7, i = l >> 3;
  int b32 = 4 * (xcd + 8 * (i >> 2)) + (i & 3);
  wfc2s[tid] = Wfc2[tid];
  wfc2s[tid + 256] = Wfc2[tid + 256];
  int lane = tid & 63, wid = tid >> 6;
  int c16 = lane & 15, q = lane >> 4;
  f32x4 acc[2][4];
#pragma unroll
  for (int ii = 0; ii < 2; ++ii)
#pragma unroll
    for (int jj = 0; jj < 4; ++jj) acc[ii][jj] = f32x4{0.f, 0.f, 0.f, 0.f};
  const unsigned short* Ab = H + (size_t)b32 * 32 * 1024 + 512;
#pragma unroll
  for (int kt = 0; kt < 8; ++kt) {
    int k0 = kt * 64;
    __syncthreads();
    {
      int p = tid;
      int row = p >> 3, u = p & 7, ch = u ^ (row & 7);
      async_copy16(Ab + row * 1024 + k0 + ch * 8, ldsA + p * 8);
    }
#pragma unroll
    for (int rd = 0; rd < 8; ++rd) {
      int p = rd * 256 + tid;
      int row = p >> 3, u = p & 7, ch = u ^ (row & 7);
      async_copy16(Wfc1b + row * 512 + k0 + ch * 8, ldsB + p * 8);
    }
    __syncthreads();
#pragma unroll
    for (int s = 0; s < 2; ++s) {
      bf16x8 a[2], b[4];
#pragma unroll
      for (int mf = 0; mf < 2; ++mf) {
        int row = mf * 16 + c16;
        int slot = row * 8 + ((s * 4 + q) ^ (row & 7));
        a[mf] = *(const bf16x8*)(ldsA + slot * 8);
      }
#pragma unroll
      for (int nf = 0; nf < 4; ++nf) {
        int row = wid * 64 + nf * 16 + c16;
        int slot = row * 8 + ((s * 4 + q) ^ (row & 7));
        b[nf] = *(const bf16x8*)(ldsB + slot * 8);
      }
#pragma unroll
      for (int mf = 0; mf < 2; ++mf)
#pragma unroll
        for (int nf = 0; nf < 4; ++nf)
          acc[mf][nf] = __builtin_amdgcn_mfma_f32_16x16x32_bf16(a[mf], b[nf], acc[mf][nf], 0, 0, 0);
    }
  }
  float part[2][2][4];
#pragma unroll
  for (int d = 0; d < 2; ++d)
#pragma unroll
    for (int mf = 0; mf < 2; ++mf)
#pragma unroll
      for (int r = 0; r < 4; ++r) part[d][mf][r] = 0.f;
#pragma unroll
  for (int nf = 0; nf < 4; ++nf) {
    int col = wid * 64 + nf * 16 + c16;
    float w0 = wfc2s[col], w1 = wfc2s[256 + col], bv = bfc1[col];
#pragma unroll
    for (int mf = 0; mf < 2; ++mf)
#pragma unroll
      for (int r = 0; r < 4; ++r) {
        float v = acc[mf][nf][r] + bv;
        v = v > 0.f ? v : 0.f;
        part[0][mf][r] += v * w0;
        part[1][mf][r] += v * w1;
      }
  }
#pragma unroll
  for (int st = 1; st < 16; st <<= 1)
#pragma unroll
    for (int d = 0; d < 2; ++d)
#pragma unroll
      for (int mf = 0; mf < 2; ++mf)
#pragma unroll
        for (int r = 0; r < 4; ++r)
          part[d][mf][r] += __shfl_xor(part[d][mf][r], st, 64);
  if (c16 == 0) {
#pragma unroll
    for (int mf = 0; mf < 2; ++mf)
#pragma unroll
      for (int r = 0; r < 4; ++r) {
        int rl = mf * 16 + q * 4 + r;
        red[rl * 8 + wid * 2 + 0] = part[0][mf][r];
        red[rl * 8 + wid * 2 + 1] = part[1][mf][r];
      }
  }
  __syncthreads();
  if (tid < 64) {
    int rl = tid >> 1, d = tid & 1;
    float s = red[rl * 8 + d] + red[rl * 8 + 2 + d] + red[rl * 8 + 4 + d]
            + red[rl * 8 + 6 + d] + bfc2[d];
    int rg = b32 * 32 + rl;
    out[((size_t)rg * T_STEPS + t) * 2 + d] = s;
    posb[rg * 2 + d] = s;
  }
}

// ---------------- launch ----------------
extern "C" void kernel_launch(void* const* d_in, const int* in_sizes, int n_in,
                              void* d_out, int out_size, void* d_ws, size_t ws_size,
                              hipStream_t stream) {
  (void)in_sizes; (void)n_in; (void)out_size;
  const float* ctx   = (const float*)d_in[0];
  const float* pos0  = (const float*)d_in[1];
  const float* ball  = (const float*)d_in[2];
  const int*   roles = (const int*)d_in[3];
  const float* role_table = (const float*)d_in[5];
  const float* Wih0 = (const float*)d_in[6];
  const float* Whh0 = (const float*)d_in[7];
  const float* b0   = (const float*)d_in[8];
  const float* Wih1 = (const float*)d_in[9];
  const float* Whh1 = (const float*)d_in[10];
  const float* b1   = (const float*)d_in[11];
  const float* Wfc1 = (const float*)d_in[12];
  const float* bfc1 = (const float*)d_in[13];
  const float* Wfc2 = (const float*)d_in[14];
  const float* bfc2 = (const float*)d_in[15];
  const float* Winit = (const float*)d_in[16];
  const float* binit = (const float*)d_in[17];
  float* out = (float*)d_out;

  char* w = (char*)d_ws;
  size_t used = 0;
  auto alloc = [&](size_t bytes) {
    char* p = w + used;
    used += (bytes + 255) & ~(size_t)255;
    return p;
  };
  unsigned short* W0p   = (unsigned short*)alloc((size_t)2048 * 512 * 2);
  unsigned short* Wc1p  = (unsigned short*)alloc((size_t)2048 * 1024 * 2);
  unsigned short* Wfc1b = (unsigned short*)alloc((size_t)256 * 512 * 2);
  float* Wposx = (float*)alloc(2048 * 4);
  float* Wposy = (float*)alloc(2048 * 4);
  float* b0p4  = (float*)alloc(2048 * 4);
  float* b1p4  = (float*)alloc(2048 * 4);
  float* posb  = (float*)alloc((size_t)NROWSP * 2 * 4);
  unsigned short* h0A = (unsigned short*)alloc((size_t)NROWSP * 512 * 2);
  unsigned short* h0B = (unsigned short*)alloc((size_t)NROWSP * 512 * 2);
  unsigned short* h1A = (unsigned short*)alloc((size_t)NROWSP * 512 * 2);
  unsigned short* h1B = (unsigned short*)alloc((size_t)NROWSP * 512 * 2);
  float* c0   = (float*)alloc((size_t)512 * NROWSP * 4);
  float* c1   = (float*)alloc((size_t)512 * NROWSP * 4);
  unsigned short* SP2 = (unsigned short*)alloc((size_t)NROWSP * 2048 * 2);
  // Xs/Wsp alias the dead-until-t0 h0B/h1B buffers (used only by k_static)
  unsigned short* Xs  = h0B;     // 17.3 MB <= 23.1 MB
  unsigned short* Wsp = h1B;     // 1.6 MB

  const bool use_p = (ws_size >= used + (1u << 20));

  if (use_p) {
    k_prep_w<<<2048, 512, 0, stream>>>(Whh0, Wih1, Whh1, Wih0, Wfc1, b0, b1,
                                       W0p, Wc1p, Wsp, Wfc1b, Wposx, Wposy, b0p4, b1p4);
    k_init_xs<<<NROWS, 384, 0, stream>>>(ball, ctx, roles, role_table, Xs);
    k_init_p<<<(NROWSP * 512 + 255) / 256, 256, 0, stream>>>(pos0, Winit, binit,
                                                             h0A, h1A, c0, c1, posb, SP2);
    dim3 gs(16, NBM);
    k_static<<<gs, 256, 0, stream>>>(Xs, Wsp, b0p4, SP2);
    k_persist<<<256, 512, 0, stream>>>(W0p, Wc1p, Wfc1b, SP2, b1p4, Wposx, Wposy,
                                       bfc1, Wfc2, bfc2, h0A, h0B, h1A, h1B,
                                       c0, c1, posb, out);
  } else {
    // lite fallback: R14 3-dispatch structure, no SP2 (static via GEMM)
    used = 0;
    unsigned short* W0pL   = (unsigned short*)alloc((size_t)2048 * 512 * 2);
    unsigned short* Wc1pL  = (unsigned short*)alloc((size_t)2048 * 1024 * 2);
    unsigned short* Wfc1bL = (unsigned short*)alloc((size_t)256 * 512 * 2);
    float* WposxL = (float*)alloc(2048 * 4);
    float* WposyL = (float*)alloc(2048 * 4);
    float* b0p4L  = (float*)alloc(2048 * 4);
    float* b1p4L  = (float*)alloc(2048 * 4);
    float* posbL  = (float*)alloc((size_t)NROWS * 2 * 4);
    unsigned short* Hc0 = (unsigned short*)alloc((size_t)NROWS * 1024 * 2);
    float* c0L   = (float*)alloc((size_t)NROWS * 512 * 4);
    float* c1L   = (float*)alloc((size_t)NROWS * 512 * 4);
    unsigned short* Hc1 = (unsigned short*)alloc((size_t)NROWS * 1024 * 2);
    unsigned short* XsL  = (unsigned short*)alloc((size_t)NROWS * 384 * 2);
    unsigned short* WspL = (unsigned short*)alloc((size_t)2048 * 384 * 2);

    k_prep_w<<<2048, 512, 0, stream>>>(Whh0, Wih1, Whh1, Wih0, Wfc1, b0, b1,
                                       W0pL, Wc1pL, WspL, Wfc1bL, WposxL, WposyL, b0p4L, b1p4L);
    k_init_xs<<<NROWS, 384, 0, stream>>>(ball, ctx, roles, role_table, XsL);
    k_init_state<<<(NROWS * 512 + 255) / 256, 256, 0, stream>>>(pos0, Winit, binit, Hc0,
                                                                c0L, c1L, posbL);
    for (int t = 0; t < T_STEPS; ++t) {
      unsigned short* cur = (t & 1) ? Hc1 : Hc0;
      unsigned short* nxt = (t & 1) ? Hc0 : Hc1;
      k_s1_lite<<<704, 512, 0, stream>>>(cur, XsL, W0pL, WspL, b0p4L,
                                         WposxL, WposyL, posbL, c0L, nxt);
      k_s2_8<<<704, 512, 0, stream>>>(nxt, cur, Wc1pL, b1p4L, c1L, nxt);
      k_s3<<<704, 256, 0, stream>>>(nxt, Wfc1bL, bfc1, Wfc2, bfc2, out, posbL, t);
    }
  }
}